// Round 5
// baseline (422.307 us; speedup 1.0000x reference)
//
#include <hip/hip_runtime.h>
#include <hip/hip_bf16.h>

typedef __hip_bfloat16 HB;
typedef __attribute__((ext_vector_type(8))) short short8;
typedef __attribute__((ext_vector_type(4))) short short4v;
typedef __attribute__((ext_vector_type(4))) float f32x4;
typedef __attribute__((ext_vector_type(2))) unsigned int uint2v;
typedef __attribute__((ext_vector_type(4))) unsigned int uint4v;

constexpr int Bn = 4, Nn = 2048, Dm = 128, Hh = 4;
constexpr int MN = Bn * Nn;              // 8192 rows
constexpr size_t SZ = (size_t)MN * Dm;   // 1,048,576 elems per [B,N,128] buffer

static __device__ __forceinline__ short f2bs(float x) {   // RNE
    __hip_bfloat16 h = __float2bfloat16(x);
    return __builtin_bit_cast(short, h);
}
// round-half-up bf16 pack of two f32 -> one u32 (lo16 = bf(lo), hi16 = bf(hi))
static __device__ __forceinline__ unsigned int pk2(float lo, float hi) {
    unsigned int a = __builtin_bit_cast(unsigned int, lo) + 0x8000u;
    unsigned int b = __builtin_bit_cast(unsigned int, hi) + 0x8000u;
    return (a >> 16) | (b & 0xFFFF0000u);
}

// ================= fused linear family =================
// C(slot s) = A_staged @ Ws + bs, A_staged = A + sum extras.  slot0 optionally RELU+residual.
// NW=#outputs. KBF: slot1 written bf16 (Cb) else f32 (C1). slot2 -> C2 f32.
template<int NW, int RELU, int KBF>
__global__ __launch_bounds__(256) void k_lin(
                      const float* __restrict__ A,
                      const float* __restrict__ extra, int nextra, int estride,
                      const float* __restrict__ W0, const float* __restrict__ b0,
                      const float* __restrict__ W1, const float* __restrict__ b1,
                      const float* __restrict__ W2, const float* __restrict__ b2,
                      int M, float* __restrict__ C0, HB* __restrict__ Cb,
                      float* __restrict__ C1, float* __restrict__ C2) {
    __shared__ float ldsf[16 * 128];
    const int tid = threadIdx.x;
    const int m0 = blockIdx.x * 16;

    #pragma unroll
    for (int it = 0; it < 2; ++it) {
        int f = it * 256 + tid;                 // 512 float4 slots (16 rows x 32)
        int r = f >> 5, c = f & 31;
        int row = m0 + r;
        float4 v = make_float4(0.f, 0.f, 0.f, 0.f);
        if (row < M) {
            v = ((const float4*)(A + (size_t)row * 128))[c];
            for (int e = 0; e < nextra; ++e) {
                float4 w = ((const float4*)(extra + (size_t)e * estride + (size_t)row * 128))[c];
                v.x += w.x; v.y += w.y; v.z += w.z; v.w += w.w;
            }
        }
        ((float4*)ldsf)[f] = v;
    }
    __syncthreads();

    const int rg = tid >> 5;                    // 0..7 -> rows rg, rg+8
    const int c4 = (tid & 31) * 4;
    float4 acc[NW][2];
    #pragma unroll
    for (int s = 0; s < NW; ++s) {
        acc[s][0] = make_float4(0.f, 0.f, 0.f, 0.f);
        acc[s][1] = make_float4(0.f, 0.f, 0.f, 0.f);
    }
    #pragma unroll 4
    for (int k = 0; k < 128; k += 4) {
        float4 a0v = *(const float4*)(ldsf + rg * 128 + k);
        float4 a1v = *(const float4*)(ldsf + (rg + 8) * 128 + k);
        #pragma unroll
        for (int kk = 0; kk < 4; ++kk) {
            float a0 = (&a0v.x)[kk];
            float a1 = (&a1v.x)[kk];
            {
                float4 w = *(const float4*)(W0 + (k + kk) * 128 + c4);
                acc[0][0].x = fmaf(a0, w.x, acc[0][0].x); acc[0][0].y = fmaf(a0, w.y, acc[0][0].y);
                acc[0][0].z = fmaf(a0, w.z, acc[0][0].z); acc[0][0].w = fmaf(a0, w.w, acc[0][0].w);
                acc[0][1].x = fmaf(a1, w.x, acc[0][1].x); acc[0][1].y = fmaf(a1, w.y, acc[0][1].y);
                acc[0][1].z = fmaf(a1, w.z, acc[0][1].z); acc[0][1].w = fmaf(a1, w.w, acc[0][1].w);
            }
            if (NW >= 2) {
                float4 w = *(const float4*)(W1 + (k + kk) * 128 + c4);
                acc[1][0].x = fmaf(a0, w.x, acc[1][0].x); acc[1][0].y = fmaf(a0, w.y, acc[1][0].y);
                acc[1][0].z = fmaf(a0, w.z, acc[1][0].z); acc[1][0].w = fmaf(a0, w.w, acc[1][0].w);
                acc[1][1].x = fmaf(a1, w.x, acc[1][1].x); acc[1][1].y = fmaf(a1, w.y, acc[1][1].y);
                acc[1][1].z = fmaf(a1, w.z, acc[1][1].z); acc[1][1].w = fmaf(a1, w.w, acc[1][1].w);
            }
            if (NW == 3) {
                float4 w = *(const float4*)(W2 + (k + kk) * 128 + c4);
                acc[2][0].x = fmaf(a0, w.x, acc[2][0].x); acc[2][0].y = fmaf(a0, w.y, acc[2][0].y);
                acc[2][0].z = fmaf(a0, w.z, acc[2][0].z); acc[2][0].w = fmaf(a0, w.w, acc[2][0].w);
                acc[2][1].x = fmaf(a1, w.x, acc[2][1].x); acc[2][1].y = fmaf(a1, w.y, acc[2][1].y);
                acc[2][1].z = fmaf(a1, w.z, acc[2][1].z); acc[2][1].w = fmaf(a1, w.w, acc[2][1].w);
            }
        }
    }

    float4 bb0 = *(const float4*)(b0 + c4);
    #pragma unroll
    for (int rr = 0; rr < 2; ++rr) {
        int r = rg + rr * 8, row = m0 + r;
        if (row >= M) continue;
        float4 v = acc[0][rr];
        v.x += bb0.x; v.y += bb0.y; v.z += bb0.z; v.w += bb0.w;
        if (RELU) {
            float4 st = *(float4*)(ldsf + r * 128 + c4);
            v.x = fmaxf(v.x, 0.f) + st.x; v.y = fmaxf(v.y, 0.f) + st.y;
            v.z = fmaxf(v.z, 0.f) + st.z; v.w = fmaxf(v.w, 0.f) + st.w;
        }
        *(float4*)(C0 + (size_t)row * 128 + c4) = v;
        if (NW >= 2) {
            float4 bb1 = *(const float4*)(b1 + c4);
            float4 u = acc[1][rr];
            u.x += bb1.x; u.y += bb1.y; u.z += bb1.z; u.w += bb1.w;
            if (KBF) {
                uint2v p; p[0] = pk2(u.x, u.y); p[1] = pk2(u.z, u.w);
                *(short4v*)((short*)Cb + (size_t)row * 128 + c4) = __builtin_bit_cast(short4v, p);
            } else {
                *(float4*)(C1 + (size_t)row * 128 + c4) = u;
            }
        }
        if (NW == 3) {
            float4 bb2 = *(const float4*)(b2 + c4);
            float4 u = acc[2][rr];
            u.x += bb2.x; u.y += bb2.y; u.z += bb2.z; u.w += bb2.w;
            *(float4*)(C2 + (size_t)row * 128 + c4) = u;
        }
    }
}

// ================= V transpose+convert with k-slot permutation =================
// Vt[bh][dh=32][slot=2048], where per 32-m block, slot s holds m = pi(s):
//   pi(q*8+j) = q*4+j (j<4), 16+q*4+(j-4) (j>=4)
// i.e. V[m] lands at slot = (m&~31) + ((m&15)>>2)*8 + ((m>>4)&1)*4 + (m&3)
__global__ void k_vt(const float* __restrict__ Vp, HB* __restrict__ Vt) {
    const int bh = blockIdx.x, b = bh >> 2, h = bh & 3;
    const int n0 = blockIdx.y * 64;
    __shared__ float t[64][33];
    const int tid = threadIdx.x;
    #pragma unroll
    for (int it = 0; it < 2; ++it) {
        int f = it * 256 + tid;
        int r = f >> 3, c4 = f & 7;
        float4 v = *(const float4*)(Vp + (size_t)(b * Nn + n0 + r) * Dm + h * 32 + c4 * 4);
        t[r][c4 * 4 + 0] = v.x; t[r][c4 * 4 + 1] = v.y;
        t[r][c4 * 4 + 2] = v.z; t[r][c4 * 4 + 3] = v.w;
    }
    __syncthreads();
    const int c = tid >> 3, g = tid & 7;          // dh=c, m-range g*8..g*8+7
    #pragma unroll
    for (int half = 0; half < 2; ++half) {
        int m = g * 8 + half * 4;                 // aligned group of 4
        int slot = (m & ~31) + (((m & 15) >> 2) << 3) + (((m >> 4) & 1) << 2);
        short4v p;
        #pragma unroll
        for (int k = 0; k < 4; ++k) p[k] = f2bs(t[m + k][c]);
        *(short4v*)((short*)Vt + (size_t)(bh * 32 + c) * Nn + n0 + slot) = p;
    }
}

// ================= MFMA sigmoid attention: no in-loop LDS, K=32 only =================
// grid: 16 bh * 64 qg, block 256 (4 waves). Wave w: q rows qg*32..+32, m in [w*512,+512).
// S^T = K.Q^T (16x16x32, D[m'][q]); sigmoid in-register; packed into K=32 B-frags via the
// pi-permutation matching Vt's layout; O^T += Vt~ . S~ (16x16x32, D[dh'][q]).
// Block epilogue: reduce 4 wave-partials in LDS -> single Opart f32 write.
__global__ __launch_bounds__(256) void k_attn3(const float* __restrict__ Qp, const HB* __restrict__ Kbf,
                                               const HB* __restrict__ Vt, float* __restrict__ Opart) {
    const int tid = threadIdx.x;
    const int w = tid >> 6, lane = tid & 63, l15 = lane & 15, quad = lane >> 4;
    const int bh = blockIdx.x >> 6, qg = blockIdx.x & 63;
    const int b = bh >> 2, h = bh & 3;

    __shared__ float ldsacc[4][32][36];

    const float nscale = -0.08838834764831845f;   // -1/sqrt(128)

    // Q B-frags (16x16x32): B[k=dh=quad*8+j][n=q=l15]
    short8 aq[2];
    #pragma unroll
    for (int qa = 0; qa < 2; ++qa) {
        const float* qp = Qp + (size_t)(b * Nn + qg * 32 + qa * 16 + l15) * 128 + h * 32 + quad * 8;
        float4 q0 = *(const float4*)qp;
        float4 q1 = *(const float4*)(qp + 4);
        uint4v u;
        u[0] = pk2(q0.x, q0.y); u[1] = pk2(q0.z, q0.w);
        u[2] = pk2(q1.x, q1.y); u[3] = pk2(q1.z, q1.w);
        aq[qa] = __builtin_bit_cast(short8, u);
    }

    f32x4 zero = {0.f, 0.f, 0.f, 0.f};
    f32x4 o[2][2];
    o[0][0] = zero; o[0][1] = zero; o[1][0] = zero; o[1][1] = zero;

    const short* Kb = (const short*)Kbf + (size_t)b * Nn * 128 + h * 32;
    const short* Vb = (const short*)Vt + (size_t)bh * 32 * Nn;

    for (int m0 = w * 512; m0 < w * 512 + 512; m0 += 64) {
        // K A-frags (16x16x32): A[m'=l15][k=dh=quad*8+j]
        short8 kb[4];
        #pragma unroll
        for (int mc = 0; mc < 4; ++mc)
            kb[mc] = *(const short8*)(Kb + (size_t)(m0 + mc * 16 + l15) * 128 + quad * 8);
        // V~ A-frags (16x16x32, permuted k): A[dh'=l15][k=quad*8+j]
        short8 vf[2][2];
        #pragma unroll
        for (int t = 0; t < 2; ++t)
            #pragma unroll
            for (int u = 0; u < 2; ++u)
                vf[t][u] = *(const short8*)(Vb + (size_t)(t * 16 + l15) * Nn + m0 + u * 32 + quad * 8);

        #pragma unroll
        for (int qa = 0; qa < 2; ++qa) {
            // S^T chunks: D[m'=quad*4+r][q=l15], chunk mc covers m-local mc*16..+15
            f32x4 s[4];
            #pragma unroll
            for (int mc = 0; mc < 4; ++mc)
                s[mc] = __builtin_amdgcn_mfma_f32_16x16x32_bf16(kb[mc], aq[qa], zero, 0, 0, 0);
            #pragma unroll
            for (int u = 0; u < 2; ++u) {
                f32x4 lo = s[2 * u], hi = s[2 * u + 1];
                float p0 = __builtin_amdgcn_rcpf(1.f + __expf(lo[0] * nscale));
                float p1 = __builtin_amdgcn_rcpf(1.f + __expf(lo[1] * nscale));
                float p2 = __builtin_amdgcn_rcpf(1.f + __expf(lo[2] * nscale));
                float p3 = __builtin_amdgcn_rcpf(1.f + __expf(lo[3] * nscale));
                float p4 = __builtin_amdgcn_rcpf(1.f + __expf(hi[0] * nscale));
                float p5 = __builtin_amdgcn_rcpf(1.f + __expf(hi[1] * nscale));
                float p6 = __builtin_amdgcn_rcpf(1.f + __expf(hi[2] * nscale));
                float p7 = __builtin_amdgcn_rcpf(1.f + __expf(hi[3] * nscale));
                // B[k=quad*8+j][n=q=l15]: j 0..3 <- chunk lo (m-local quad*4+r),
                //                         j 4..7 <- chunk hi (m-local 16+quad*4+r)  == pi
                uint4v pu;
                pu[0] = pk2(p0, p1); pu[1] = pk2(p2, p3);
                pu[2] = pk2(p4, p5); pu[3] = pk2(p6, p7);
                short8 pf = __builtin_bit_cast(short8, pu);
                #pragma unroll
                for (int t = 0; t < 2; ++t)
                    o[qa][t] = __builtin_amdgcn_mfma_f32_16x16x32_bf16(vf[t][u], pf, o[qa][t], 0, 0, 0);
            }
        }
    }

    // wave-partial -> LDS: row q = qa*16+l15, cols dh = t*16+quad*4 (+r), f32x4
    #pragma unroll
    for (int qa = 0; qa < 2; ++qa)
        #pragma unroll
        for (int t = 0; t < 2; ++t)
            *(f32x4*)&ldsacc[w][qa * 16 + l15][t * 16 + quad * 4] = o[qa][t];
    __syncthreads();
    const int row = tid >> 3, cc = (tid & 7) * 4;
    f32x4 r0 = *(f32x4*)&ldsacc[0][row][cc];
    f32x4 r1 = *(f32x4*)&ldsacc[1][row][cc];
    f32x4 r2 = *(f32x4*)&ldsacc[2][row][cc];
    f32x4 r3 = *(f32x4*)&ldsacc[3][row][cc];
    f32x4 sum = (r0 + r1) + (r2 + r3);
    *(f32x4*)(Opart + (size_t)(b * Nn + qg * 32 + row) * 128 + h * 32 + cc) = sum;
}

// ================= PMA attention, 8-way m-split partials =================
__global__ void k_pma2(const float* __restrict__ S, const float* __restrict__ Wq, const float* __restrict__ bq,
                       const float* __restrict__ Kp, const float* __restrict__ Vp,
                       float* __restrict__ P0part) {
    const int bh = blockIdx.x, b = bh >> 2, h = bh & 3;
    const int ms = blockIdx.y;
    const int tid = threadIdx.x;
    __shared__ float4 qs4[8];
    float* qs = (float*)qs4;
    if (tid < 32) {
        float a = bq[h * 32 + tid];
        for (int k = 0; k < 128; ++k)
            a = fmaf(S[k], Wq[k * Dm + h * 32 + tid], a);
        qs[tid] = a;
    }
    __syncthreads();

    float4 q[8];
    #pragma unroll
    for (int i = 0; i < 8; ++i) q[i] = qs4[i];

    const size_t base = (size_t)b * Nn * Dm + h * 32;
    const float nscale = -0.08838834764831845f;
    const int m = ms * 256 + tid;

    const float4* kp = (const float4*)(Kp + base + (size_t)m * Dm);
    const float4* vp = (const float4*)(Vp + base + (size_t)m * Dm);
    float d0 = 0.f, d1 = 0.f, d2 = 0.f, d3 = 0.f;
    #pragma unroll
    for (int c = 0; c < 8; c += 4) {
        float4 k0 = kp[c+0], k1 = kp[c+1], k2 = kp[c+2], k3 = kp[c+3];
        d0 += q[c+0].x*k0.x + q[c+0].y*k0.y + q[c+0].z*k0.z + q[c+0].w*k0.w;
        d1 += q[c+1].x*k1.x + q[c+1].y*k1.y + q[c+1].z*k1.z + q[c+1].w*k1.w;
        d2 += q[c+2].x*k2.x + q[c+2].y*k2.y + q[c+2].z*k2.z + q[c+2].w*k2.w;
        d3 += q[c+3].x*k3.x + q[c+3].y*k3.y + q[c+3].z*k3.z + q[c+3].w*k3.w;
    }
    float dot = (d0 + d1) + (d2 + d3);
    float a = __builtin_amdgcn_rcpf(1.f + __expf(dot * nscale));
    float4 acc[8];
    #pragma unroll
    for (int c = 0; c < 8; ++c) {
        float4 vv = vp[c];
        acc[c].x = a * vv.x; acc[c].y = a * vv.y; acc[c].z = a * vv.z; acc[c].w = a * vv.w;
    }
    #pragma unroll
    for (int off = 1; off < 64; off <<= 1) {
        #pragma unroll
        for (int c = 0; c < 8; ++c) {
            acc[c].x += __shfl_xor(acc[c].x, off);
            acc[c].y += __shfl_xor(acc[c].y, off);
            acc[c].z += __shfl_xor(acc[c].z, off);
            acc[c].w += __shfl_xor(acc[c].w, off);
        }
    }
    __shared__ float red[4][32];
    const int wave = tid >> 6, lane = tid & 63;
    if (lane == 0) {
        #pragma unroll
        for (int c = 0; c < 8; ++c) {
            red[wave][c*4+0] = acc[c].x; red[wave][c*4+1] = acc[c].y;
            red[wave][c*4+2] = acc[c].z; red[wave][c*4+3] = acc[c].w;
        }
    }
    __syncthreads();
    if (tid < 32) {
        float t = (red[0][tid] + red[1][tid]) + (red[2][tid] + red[3][tid]);
        if (ms == 0) t += qs[tid];
        P0part[ms * 512 + b * 128 + h * 32 + tid] = t;
    }
}

// ================= final projection =================
__global__ void k_final(const float* __restrict__ P, const float* __restrict__ pW,
                        const float* __restrict__ pb, float* __restrict__ out) {
    const int b = blockIdx.x, c = threadIdx.x;
    __shared__ float ps[128];
    if (c < 128) ps[c] = P[b * Dm + c];
    __syncthreads();
    float a = pb[c];
    #pragma unroll 8
    for (int k = 0; k < 128; ++k)
        a = fmaf(ps[k], pW[k * 256 + c], a);
    out[b * 256 + c] = a;
}

extern "C" void kernel_launch(void* const* d_in, const int* in_sizes, int n_in,
                              void* d_out, int out_size, void* d_ws, size_t ws_size,
                              hipStream_t stream) {
    const float* X = (const float*)d_in[0];
    auto W = [&](int i) { return (const float*)d_in[i]; };
    float* ws = (float*)d_ws;

    // 5 slots of SZ floats (4 MB) = 20 MB:
    //  s0: Qp(L0) -> X1(in-place) -> K2
    //  s1: Vp(L0) -> Vp(L1) -> V2
    //  s2: Opart (L0, L1)
    //  s3: Qp(L1) -> X2(in-place)
    //  s4: Kbf(2MB)+Vt(2MB) bf16; later P0part(16KB)+Pp
    float* s0 = ws + 0 * SZ;
    float* s1 = ws + 1 * SZ;
    float* s2 = ws + 2 * SZ;
    float* s3 = ws + 3 * SZ;
    HB*    Kbf = (HB*)(ws + 4 * SZ);
    HB*    Vt  = Kbf + SZ;
    float* P0part = ws + 4 * SZ;       // 8 x 512 floats
    float* Pp     = P0part + 8192;     // 512 floats

    const int GL = MN / 16;            // 512 blocks
    dim3 vt_grid(Bn * Hh, Nn / 64);
    const int attn_blocks = Bn * Hh * (Nn / 32);   // 1024
    dim3 pma_grid(Bn * Hh, 8);
    const float* nul = nullptr;

    // ---- SAB layer 0 ----
    k_lin<3,0,1><<<GL, 256, 0, stream>>>(X, nul, 0, 0, W(1), W(2), W(3), W(4), W(5), W(6),
                                         MN, s0, Kbf, nullptr, s1);          // Qp0, Kbf, Vp0
    k_vt<<<vt_grid, 256, 0, stream>>>(s1, Vt);
    k_attn3<<<attn_blocks, 256, 0, stream>>>(s0, Kbf, Vt, s2);
    k_lin<1,1,0><<<GL, 256, 0, stream>>>(s0, s2, 1, (int)SZ, W(7), W(8), nul, nul, nul, nul,
                                         MN, s0, nullptr, nullptr, nullptr); // X1 in-place

    // ---- SAB layer 1 ----
    k_lin<3,0,1><<<GL, 256, 0, stream>>>(s0, nul, 0, 0, W(9), W(10), W(11), W(12), W(13), W(14),
                                         MN, s3, Kbf, nullptr, s1);          // Qp1, Kbf, Vp1
    k_vt<<<vt_grid, 256, 0, stream>>>(s1, Vt);
    k_attn3<<<attn_blocks, 256, 0, stream>>>(s3, Kbf, Vt, s2);
    k_lin<1,1,0><<<GL, 256, 0, stream>>>(s3, s2, 1, (int)SZ, W(15), W(16), nul, nul, nul, nul,
                                         MN, s3, nullptr, nullptr, nullptr); // X2 in-place

    // ---- PMA ----
    k_lin<2,0,0><<<GL, 256, 0, stream>>>(s3, nul, 0, 0, W(19), W(20), W(21), W(22), nul, nul,
                                         MN, s0, nullptr, s1, nullptr);      // K2, V2
    k_pma2<<<pma_grid, 256, 0, stream>>>((const float*)d_in[25], W(17), W(18), s0, s1, P0part);
    k_lin<1,1,0><<<1, 256, 0, stream>>>(P0part, P0part + 512, 7, 512, W(23), W(24), nul, nul, nul, nul,
                                        Bn, Pp, nullptr, nullptr, nullptr);  // Pp

    // ---- final projection ----
    k_final<<<Bn, 256, 0, stream>>>(Pp, (const float*)d_in[26], (const float*)d_in[27], (float*)d_out);
}

// Round 7
// 251.598 us; speedup vs baseline: 1.6785x; 1.6785x over previous
//
#include <hip/hip_runtime.h>
#include <hip/hip_bf16.h>

typedef __hip_bfloat16 HB;
typedef __attribute__((ext_vector_type(8))) short short8;
typedef __attribute__((ext_vector_type(4))) short short4v;
typedef __attribute__((ext_vector_type(4))) float f32x4;
typedef __attribute__((ext_vector_type(2))) unsigned int uint2v;
typedef __attribute__((ext_vector_type(4))) unsigned int uint4v;

constexpr int Bn = 4, Nn = 2048, Dm = 128, Hh = 4;
constexpr int MN = Bn * Nn;              // 8192 rows
constexpr size_t SZ = (size_t)MN * Dm;   // 1,048,576 elems per [B,N,128] buffer

static __device__ __forceinline__ short f2bs(float x) {   // RNE
    __hip_bfloat16 h = __float2bfloat16(x);
    return __builtin_bit_cast(short, h);
}
// round-half-up bf16 pack of two f32 -> one u32 (lo16 = bf(lo), hi16 = bf(hi))
static __device__ __forceinline__ unsigned int pk2(float lo, float hi) {
    unsigned int a = __builtin_bit_cast(unsigned int, lo) + 0x8000u;
    unsigned int b = __builtin_bit_cast(unsigned int, hi) + 0x8000u;
    return (a >> 16) | (b & 0xFFFF0000u);
}

// ================= weight pre-swizzle: W f32[128k x 128c] -> Wt8 bf16 =================
// Wt8[(g*128 + c)*8 + j] = bf16(W[(g*8+j)*128 + c]),  g = k>>3 in [0,16).
// B-frag load then = one 16B load at ((kc*4+quad)*128 + col)*8.
// FIX vs R6: idx in [0,2048) per weight (was 8x over-indexed -> OOB clobber).
__global__ void k_wprep(const float* __restrict__ Wa, const float* __restrict__ Wb,
                        const float* __restrict__ Wc, const float* __restrict__ Wd,
                        const float* __restrict__ We, const float* __restrict__ Wf,
                        const float* __restrict__ Wg, const float* __restrict__ Wh,
                        const float* __restrict__ Wi, const float* __restrict__ Wj,
                        HB* __restrict__ WtAll) {
    const float* src;
    switch (blockIdx.x) {
        case 0: src = Wa; break; case 1: src = Wb; break;
        case 2: src = Wc; break; case 3: src = Wd; break;
        case 4: src = We; break; case 5: src = Wf; break;
        case 6: src = Wg; break; case 7: src = Wh; break;
        case 8: src = Wi; break; default: src = Wj; break;
    }
    HB* dst = WtAll + (size_t)blockIdx.x * 16384;
    #pragma unroll
    for (int it = 0; it < 8; ++it) {
        int idx = it * 256 + threadIdx.x;      // 0..2047: (g in [0,16)) x (c in [0,128))
        int g = idx >> 7, c = idx & 127;
        short8 p;
        #pragma unroll
        for (int j = 0; j < 8; ++j) p[j] = f2bs(src[(size_t)(g * 8 + j) * 128 + c]);
        *(short8*)((short*)dst + (size_t)idx * 8) = p;
    }
}

// ================= MFMA linear: C_s = A_bf @ W_s + b_s  (fp32 residual path) =================
// A f32 [M x 128] (+ optional extra, summed before bf16 quantize). K=128 via 4x mfma 16x16x32.
// Wave: 1 row-tile x 2 col-tiles. Block 512 thr = 8 waves = 32 rows x 128 cols. Grid 256.
// RELU: C0 = staged + relu(gemm + b), staged = A+extra reloaded in f32.
template<int NW, int RELU, int NEXTRA>
__global__ __launch_bounds__(512) void k_linm(
        const float* __restrict__ A, const float* __restrict__ extra,
        const HB* __restrict__ Wt0, const float* __restrict__ b0,
        const HB* __restrict__ Wt1, const float* __restrict__ b1,
        const HB* __restrict__ Wt2, const float* __restrict__ b2,
        float* __restrict__ C0, float* __restrict__ C1, float* __restrict__ C2) {
    const int tid = threadIdx.x;
    const int w = tid >> 6, lane = tid & 63, l15 = lane & 15, quad = lane >> 4;
    const int row0 = blockIdx.x * 32 + (w >> 2) * 16;
    const int cbase = (w & 3) * 32;

    // A-frags: A[row=l15][k=quad*8+j] packed bf16
    short8 af[4];
    #pragma unroll
    for (int kc = 0; kc < 4; ++kc) {
        const float* ap = A + (size_t)(row0 + l15) * 128 + kc * 32 + quad * 8;
        float4 x0 = *(const float4*)ap;
        float4 x1 = *(const float4*)(ap + 4);
        if (NEXTRA) {
            const float* ep = extra + (size_t)(row0 + l15) * 128 + kc * 32 + quad * 8;
            float4 e0 = *(const float4*)ep, e1 = *(const float4*)(ep + 4);
            x0.x += e0.x; x0.y += e0.y; x0.z += e0.z; x0.w += e0.w;
            x1.x += e1.x; x1.y += e1.y; x1.z += e1.z; x1.w += e1.w;
        }
        uint4v u;
        u[0] = pk2(x0.x, x0.y); u[1] = pk2(x0.z, x0.w);
        u[2] = pk2(x1.x, x1.y); u[3] = pk2(x1.z, x1.w);
        af[kc] = __builtin_bit_cast(short8, u);
    }

    f32x4 zero = {0.f, 0.f, 0.f, 0.f};
    #pragma unroll
    for (int ct = 0; ct < 2; ++ct) {
        const int col = cbase + ct * 16 + l15;
        #pragma unroll
        for (int s = 0; s < NW; ++s) {
            const HB* Wt = (s == 0) ? Wt0 : (s == 1) ? Wt1 : Wt2;
            const float* bs = (s == 0) ? b0 : (s == 1) ? b1 : b2;
            float* Cs = (s == 0) ? C0 : (s == 1) ? C1 : C2;
            f32x4 acc = zero;
            #pragma unroll
            for (int kc = 0; kc < 4; ++kc) {
                short8 bf = *(const short8*)((const short*)Wt + ((size_t)(kc * 4 + quad) * 128 + col) * 8);
                acc = __builtin_amdgcn_mfma_f32_16x16x32_bf16(af[kc], bf, acc, 0, 0, 0);
            }
            float bb = bs[col];
            #pragma unroll
            for (int r = 0; r < 4; ++r) {
                int row = row0 + quad * 4 + r;
                float v = acc[r] + bb;
                if (RELU) {
                    float st = A[(size_t)row * 128 + col];
                    if (NEXTRA) st += extra[(size_t)row * 128 + col];
                    v = fmaxf(v, 0.f) + st;
                }
                Cs[(size_t)row * 128 + col] = v;
            }
        }
    }
}

// ================= f32 -> bf16 convert =================
__global__ void k_cvt(const float* __restrict__ in, HB* __restrict__ out, int n) {
    int i = (blockIdx.x * 256 + threadIdx.x) * 4;
    if (i + 3 < n) {
        float4 v = *(const float4*)(in + i);
        uint2v p; p[0] = pk2(v.x, v.y); p[1] = pk2(v.z, v.w);
        *(short4v*)((short*)out + i) = __builtin_bit_cast(short4v, p);
    }
}

// ================= V transpose+convert with k-slot permutation (UNCHANGED, passing) =================
__global__ void k_vt(const float* __restrict__ Vp, HB* __restrict__ Vt) {
    const int bh = blockIdx.x, b = bh >> 2, h = bh & 3;
    const int n0 = blockIdx.y * 64;
    __shared__ float t[64][33];
    const int tid = threadIdx.x;
    #pragma unroll
    for (int it = 0; it < 2; ++it) {
        int f = it * 256 + tid;
        int r = f >> 3, c4 = f & 7;
        float4 v = *(const float4*)(Vp + (size_t)(b * Nn + n0 + r) * Dm + h * 32 + c4 * 4);
        t[r][c4 * 4 + 0] = v.x; t[r][c4 * 4 + 1] = v.y;
        t[r][c4 * 4 + 2] = v.z; t[r][c4 * 4 + 3] = v.w;
    }
    __syncthreads();
    const int c = tid >> 3, g = tid & 7;
    #pragma unroll
    for (int half = 0; half < 2; ++half) {
        int m = g * 8 + half * 4;
        int slot = (m & ~31) + (((m & 15) >> 2) << 3) + (((m >> 4) & 1) << 2);
        short4v p;
        #pragma unroll
        for (int k = 0; k < 4; ++k) p[k] = f2bs(t[m + k][c]);
        *(short4v*)((short*)Vt + (size_t)(bh * 32 + c) * Nn + n0 + slot) = p;
    }
}

// ================= MFMA sigmoid attention (UNCHANGED, passing) =================
__global__ __launch_bounds__(256) void k_attn3(const float* __restrict__ Qp, const HB* __restrict__ Kbf,
                                               const HB* __restrict__ Vt, float* __restrict__ Opart) {
    const int tid = threadIdx.x;
    const int w = tid >> 6, lane = tid & 63, l15 = lane & 15, quad = lane >> 4;
    const int bh = blockIdx.x >> 6, qg = blockIdx.x & 63;
    const int b = bh >> 2, h = bh & 3;

    __shared__ float ldsacc[4][32][36];

    const float nscale = -0.08838834764831845f;   // -1/sqrt(128)

    short8 aq[2];
    #pragma unroll
    for (int qa = 0; qa < 2; ++qa) {
        const float* qp = Qp + (size_t)(b * Nn + qg * 32 + qa * 16 + l15) * 128 + h * 32 + quad * 8;
        float4 q0 = *(const float4*)qp;
        float4 q1 = *(const float4*)(qp + 4);
        uint4v u;
        u[0] = pk2(q0.x, q0.y); u[1] = pk2(q0.z, q0.w);
        u[2] = pk2(q1.x, q1.y); u[3] = pk2(q1.z, q1.w);
        aq[qa] = __builtin_bit_cast(short8, u);
    }

    f32x4 zero = {0.f, 0.f, 0.f, 0.f};
    f32x4 o[2][2];
    o[0][0] = zero; o[0][1] = zero; o[1][0] = zero; o[1][1] = zero;

    const short* Kb = (const short*)Kbf + (size_t)b * Nn * 128 + h * 32;
    const short* Vb = (const short*)Vt + (size_t)bh * 32 * Nn;

    for (int m0 = w * 512; m0 < w * 512 + 512; m0 += 64) {
        short8 kb[4];
        #pragma unroll
        for (int mc = 0; mc < 4; ++mc)
            kb[mc] = *(const short8*)(Kb + (size_t)(m0 + mc * 16 + l15) * 128 + quad * 8);
        short8 vf[2][2];
        #pragma unroll
        for (int t = 0; t < 2; ++t)
            #pragma unroll
            for (int u = 0; u < 2; ++u)
                vf[t][u] = *(const short8*)(Vb + (size_t)(t * 16 + l15) * Nn + m0 + u * 32 + quad * 8);

        #pragma unroll
        for (int qa = 0; qa < 2; ++qa) {
            f32x4 s[4];
            #pragma unroll
            for (int mc = 0; mc < 4; ++mc)
                s[mc] = __builtin_amdgcn_mfma_f32_16x16x32_bf16(kb[mc], aq[qa], zero, 0, 0, 0);
            #pragma unroll
            for (int u = 0; u < 2; ++u) {
                f32x4 lo = s[2 * u], hi = s[2 * u + 1];
                float p0 = __builtin_amdgcn_rcpf(1.f + __expf(lo[0] * nscale));
                float p1 = __builtin_amdgcn_rcpf(1.f + __expf(lo[1] * nscale));
                float p2 = __builtin_amdgcn_rcpf(1.f + __expf(lo[2] * nscale));
                float p3 = __builtin_amdgcn_rcpf(1.f + __expf(lo[3] * nscale));
                float p4 = __builtin_amdgcn_rcpf(1.f + __expf(hi[0] * nscale));
                float p5 = __builtin_amdgcn_rcpf(1.f + __expf(hi[1] * nscale));
                float p6 = __builtin_amdgcn_rcpf(1.f + __expf(hi[2] * nscale));
                float p7 = __builtin_amdgcn_rcpf(1.f + __expf(hi[3] * nscale));
                uint4v pu;
                pu[0] = pk2(p0, p1); pu[1] = pk2(p2, p3);
                pu[2] = pk2(p4, p5); pu[3] = pk2(p6, p7);
                short8 pf = __builtin_bit_cast(short8, pu);
                #pragma unroll
                for (int t = 0; t < 2; ++t)
                    o[qa][t] = __builtin_amdgcn_mfma_f32_16x16x32_bf16(vf[t][u], pf, o[qa][t], 0, 0, 0);
            }
        }
    }

    #pragma unroll
    for (int qa = 0; qa < 2; ++qa)
        #pragma unroll
        for (int t = 0; t < 2; ++t)
            *(f32x4*)&ldsacc[w][qa * 16 + l15][t * 16 + quad * 4] = o[qa][t];
    __syncthreads();
    const int row = tid >> 3, cc = (tid & 7) * 4;
    f32x4 r0 = *(f32x4*)&ldsacc[0][row][cc];
    f32x4 r1 = *(f32x4*)&ldsacc[1][row][cc];
    f32x4 r2 = *(f32x4*)&ldsacc[2][row][cc];
    f32x4 r3 = *(f32x4*)&ldsacc[3][row][cc];
    f32x4 sum = (r0 + r1) + (r2 + r3);
    *(f32x4*)(Opart + (size_t)(b * Nn + qg * 32 + row) * 128 + h * 32 + cc) = sum;
}

// ================= PMA attention, 8-way m-split partials (UNCHANGED, passing) =================
__global__ void k_pma2(const float* __restrict__ S, const float* __restrict__ Wq, const float* __restrict__ bq,
                       const float* __restrict__ Kp, const float* __restrict__ Vp,
                       float* __restrict__ P0part) {
    const int bh = blockIdx.x, b = bh >> 2, h = bh & 3;
    const int ms = blockIdx.y;
    const int tid = threadIdx.x;
    __shared__ float4 qs4[8];
    float* qs = (float*)qs4;
    if (tid < 32) {
        float a = bq[h * 32 + tid];
        for (int k = 0; k < 128; ++k)
            a = fmaf(S[k], Wq[k * Dm + h * 32 + tid], a);
        qs[tid] = a;
    }
    __syncthreads();

    float4 q[8];
    #pragma unroll
    for (int i = 0; i < 8; ++i) q[i] = qs4[i];

    const size_t base = (size_t)b * Nn * Dm + h * 32;
    const float nscale = -0.08838834764831845f;
    const int m = ms * 256 + tid;

    const float4* kp = (const float4*)(Kp + base + (size_t)m * Dm);
    const float4* vp = (const float4*)(Vp + base + (size_t)m * Dm);
    float d0 = 0.f, d1 = 0.f, d2 = 0.f, d3 = 0.f;
    #pragma unroll
    for (int c = 0; c < 8; c += 4) {
        float4 k0 = kp[c+0], k1 = kp[c+1], k2 = kp[c+2], k3 = kp[c+3];
        d0 += q[c+0].x*k0.x + q[c+0].y*k0.y + q[c+0].z*k0.z + q[c+0].w*k0.w;
        d1 += q[c+1].x*k1.x + q[c+1].y*k1.y + q[c+1].z*k1.z + q[c+1].w*k1.w;
        d2 += q[c+2].x*k2.x + q[c+2].y*k2.y + q[c+2].z*k2.z + q[c+2].w*k2.w;
        d3 += q[c+3].x*k3.x + q[c+3].y*k3.y + q[c+3].z*k3.z + q[c+3].w*k3.w;
    }
    float dot = (d0 + d1) + (d2 + d3);
    float a = __builtin_amdgcn_rcpf(1.f + __expf(dot * nscale));
    float4 acc[8];
    #pragma unroll
    for (int c = 0; c < 8; ++c) {
        float4 vv = vp[c];
        acc[c].x = a * vv.x; acc[c].y = a * vv.y; acc[c].z = a * vv.z; acc[c].w = a * vv.w;
    }
    #pragma unroll
    for (int off = 1; off < 64; off <<= 1) {
        #pragma unroll
        for (int c = 0; c < 8; ++c) {
            acc[c].x += __shfl_xor(acc[c].x, off);
            acc[c].y += __shfl_xor(acc[c].y, off);
            acc[c].z += __shfl_xor(acc[c].z, off);
            acc[c].w += __shfl_xor(acc[c].w, off);
        }
    }
    __shared__ float red[4][32];
    const int wave = tid >> 6, lane = tid & 63;
    if (lane == 0) {
        #pragma unroll
        for (int c = 0; c < 8; ++c) {
            red[wave][c*4+0] = acc[c].x; red[wave][c*4+1] = acc[c].y;
            red[wave][c*4+2] = acc[c].z; red[wave][c*4+3] = acc[c].w;
        }
    }
    __syncthreads();
    if (tid < 32) {
        float t = (red[0][tid] + red[1][tid]) + (red[2][tid] + red[3][tid]);
        if (ms == 0) t += qs[tid];
        P0part[ms * 512 + b * 128 + h * 32 + tid] = t;
    }
}

// ================= tiny VALU linear (M=4 only) =================
__global__ __launch_bounds__(256) void k_lin_small(
                      const float* __restrict__ A,
                      const float* __restrict__ extra, int nextra, int estride,
                      const float* __restrict__ W0, const float* __restrict__ b0,
                      int M, float* __restrict__ C0) {
    __shared__ float ldsf[16 * 128];
    const int tid = threadIdx.x;

    #pragma unroll
    for (int it = 0; it < 2; ++it) {
        int f = it * 256 + tid;
        int r = f >> 5, c = f & 31;
        float4 v = make_float4(0.f, 0.f, 0.f, 0.f);
        if (r < M) {
            v = ((const float4*)(A + (size_t)r * 128))[c];
            for (int e = 0; e < nextra; ++e) {
                float4 w = ((const float4*)(extra + (size_t)e * estride + (size_t)r * 128))[c];
                v.x += w.x; v.y += w.y; v.z += w.z; v.w += w.w;
            }
        }
        ((float4*)ldsf)[f] = v;
    }
    __syncthreads();

    const int col = tid & 127;
    const int rg  = tid >> 7;                    // rows rg, rg+2
    float acc[2] = {0.f, 0.f};
    #pragma unroll 8
    for (int k = 0; k < 128; ++k) {
        float w = W0[k * 128 + col];
        acc[0] = fmaf(ldsf[rg * 128 + k], w, acc[0]);
        acc[1] = fmaf(ldsf[(rg + 2) * 128 + k], w, acc[1]);
    }
    float bb = b0[col];
    #pragma unroll
    for (int i = 0; i < 2; ++i) {
        int r = rg + 2 * i;
        if (r < M) {
            float v = fmaxf(acc[i] + bb, 0.f) + ldsf[r * 128 + col];
            C0[(size_t)r * 128 + col] = v;
        }
    }
}

// ================= final projection (UNCHANGED, passing) =================
__global__ void k_final(const float* __restrict__ P, const float* __restrict__ pW,
                        const float* __restrict__ pb, float* __restrict__ out) {
    const int b = blockIdx.x, c = threadIdx.x;
    __shared__ float ps[128];
    if (c < 128) ps[c] = P[b * Dm + c];
    __syncthreads();
    float a = pb[c];
    #pragma unroll 8
    for (int k = 0; k < 128; ++k)
        a = fmaf(ps[k], pW[k * 256 + c], a);
    out[b * 256 + c] = a;
}

extern "C" void kernel_launch(void* const* d_in, const int* in_sizes, int n_in,
                              void* d_out, int out_size, void* d_ws, size_t ws_size,
                              hipStream_t stream) {
    const float* X = (const float*)d_in[0];
    auto W = [&](int i) { return (const float*)d_in[i]; };
    float* ws = (float*)d_ws;

    // slots of SZ floats (4 MB):
    //  s0: Qp0 -> Qp1 -> K2
    //  s1: Vp0 -> Vp1 -> X2
    //  s2: Kp0 -> Opart0 -> Kp1 -> Opart1 -> V2
    //  s3: X1 -> P0part/Pp
    //  s4: Kbf(2MB) + Vt(2MB) bf16
    //  s5: WtAll (10 x 32KB bf16)
    float* s0 = ws + 0 * SZ;
    float* s1 = ws + 1 * SZ;
    float* s2 = ws + 2 * SZ;
    float* s3 = ws + 3 * SZ;
    HB*    Kbf = (HB*)(ws + 4 * SZ);
    HB*    Vt  = Kbf + SZ;
    HB*    WtAll = (HB*)(ws + 5 * SZ);
    auto Wt = [&](int idx) { return (const HB*)(WtAll + (size_t)idx * 16384); };
    float* P0part = s3;                 // 8 x 512 floats (X1 dead by then)
    float* Pp     = s3 + 8192;          // 512 floats

    const int GLM = MN / 32;            // 256 blocks for k_linm
    const int GC = (int)(SZ / 4 / 256); // 1024 blocks for cvt
    dim3 vt_grid(Bn * Hh, Nn / 64);
    const int attn_blocks = Bn * Hh * (Nn / 32);   // 1024
    dim3 pma_grid(Bn * Hh, 8);
    const float* nul = nullptr;
    const HB* nulh = nullptr;

    // ---- weight pre-swizzle: [W1,W3,W5,W7,W9,W11,W13,W15,W19,W21] -> idx 0..9 ----
    k_wprep<<<10, 256, 0, stream>>>(W(1), W(3), W(5), W(7), W(9), W(11), W(13), W(15),
                                    W(19), W(21), WtAll);

    // ---- SAB layer 0 ----
    k_linm<3,0,0><<<GLM, 512, 0, stream>>>(X, nul, Wt(0), W(2), Wt(1), W(4), Wt(2), W(6),
                                           s0, s2, s1);                      // Qp0, Kp0, Vp0
    k_cvt<<<GC, 256, 0, stream>>>(s2, Kbf, (int)SZ);
    k_vt<<<vt_grid, 256, 0, stream>>>(s1, Vt);
    k_attn3<<<attn_blocks, 256, 0, stream>>>(s0, Kbf, Vt, s2);               // Opart0
    k_linm<1,1,1><<<GLM, 512, 0, stream>>>(s0, s2, Wt(3), W(8), nulh, nul, nulh, nul,
                                           s3, nullptr, nullptr);            // X1

    // ---- SAB layer 1 ----
    k_linm<3,0,0><<<GLM, 512, 0, stream>>>(s3, nul, Wt(4), W(10), Wt(5), W(12), Wt(6), W(14),
                                           s0, s2, s1);                      // Qp1, Kp1, Vp1
    k_cvt<<<GC, 256, 0, stream>>>(s2, Kbf, (int)SZ);
    k_vt<<<vt_grid, 256, 0, stream>>>(s1, Vt);
    k_attn3<<<attn_blocks, 256, 0, stream>>>(s0, Kbf, Vt, s2);               // Opart1
    k_linm<1,1,1><<<GLM, 512, 0, stream>>>(s0, s2, Wt(7), W(16), nulh, nul, nulh, nul,
                                           s1, nullptr, nullptr);            // X2

    // ---- PMA ----
    k_linm<2,0,0><<<GLM, 512, 0, stream>>>(s1, nul, Wt(8), W(20), Wt(9), W(22), nulh, nul,
                                           s0, s2, nullptr);                 // K2, V2
    k_pma2<<<pma_grid, 256, 0, stream>>>((const float*)d_in[25], W(17), W(18), s0, s2, P0part);
    k_lin_small<<<1, 256, 0, stream>>>(P0part, P0part + 512, 7, 512, W(23), W(24), Bn, Pp);

    // ---- final projection ----
    k_final<<<Bn, 256, 0, stream>>>(Pp, (const float*)d_in[26], (const float*)d_in[27], (float*)d_out);
}

// Round 8
// 236.687 us; speedup vs baseline: 1.7842x; 1.0630x over previous
//
#include <hip/hip_runtime.h>
#include <hip/hip_bf16.h>

typedef __hip_bfloat16 HB;
typedef __attribute__((ext_vector_type(8))) short short8;
typedef __attribute__((ext_vector_type(4))) short short4v;
typedef __attribute__((ext_vector_type(4))) float f32x4;
typedef __attribute__((ext_vector_type(2))) unsigned int uint2v;
typedef __attribute__((ext_vector_type(4))) unsigned int uint4v;

constexpr int Bn = 4, Nn = 2048, Dm = 128, Hh = 4;
constexpr int MN = Bn * Nn;              // 8192 rows
constexpr size_t SZ = (size_t)MN * Dm;   // 1,048,576 elems per [B,N,128] buffer

static __device__ __forceinline__ short f2bs(float x) {   // RNE
    __hip_bfloat16 h = __float2bfloat16(x);
    return __builtin_bit_cast(short, h);
}
// round-half-up bf16 of one f32 -> u16
static __device__ __forceinline__ unsigned short f2bh(float x) {
    return (unsigned short)((__builtin_bit_cast(unsigned int, x) + 0x8000u) >> 16);
}
// round-half-up bf16 pack of two f32 -> one u32 (lo16 = bf(lo), hi16 = bf(hi))
static __device__ __forceinline__ unsigned int pk2(float lo, float hi) {
    unsigned int a = __builtin_bit_cast(unsigned int, lo) + 0x8000u;
    unsigned int b = __builtin_bit_cast(unsigned int, hi) + 0x8000u;
#if __has_builtin(__builtin_amdgcn_perm)
    return __builtin_amdgcn_perm(b, a, 0x07060302u);   // bytes [b3 b2 a3 a2]
#else
    return (a >> 16) | (b & 0xFFFF0000u);
#endif
}

// ================= weight pre-swizzle: W f32[128k x 128c] -> Wt8 bf16 =================
// Wt8[(g*128 + c)*8 + j] = bf16(W[(g*8+j)*128 + c]),  g = k>>3 in [0,16).
__global__ void k_wprep(const float* __restrict__ Wa, const float* __restrict__ Wb,
                        const float* __restrict__ Wc, const float* __restrict__ Wd,
                        const float* __restrict__ We, const float* __restrict__ Wf,
                        const float* __restrict__ Wg, const float* __restrict__ Wh,
                        const float* __restrict__ Wi, const float* __restrict__ Wj,
                        HB* __restrict__ WtAll) {
    const float* src;
    switch (blockIdx.x) {
        case 0: src = Wa; break; case 1: src = Wb; break;
        case 2: src = Wc; break; case 3: src = Wd; break;
        case 4: src = We; break; case 5: src = Wf; break;
        case 6: src = Wg; break; case 7: src = Wh; break;
        case 8: src = Wi; break; default: src = Wj; break;
    }
    HB* dst = WtAll + (size_t)blockIdx.x * 16384;
    #pragma unroll
    for (int it = 0; it < 8; ++it) {
        int idx = it * 256 + threadIdx.x;      // 0..2047: (g in [0,16)) x (c in [0,128))
        int g = idx >> 7, c = idx & 127;
        short8 p;
        #pragma unroll
        for (int j = 0; j < 8; ++j) p[j] = f2bs(src[(size_t)(g * 8 + j) * 128 + c]);
        *(short8*)((short*)dst + (size_t)idx * 8) = p;
    }
}

// ================= MFMA linear =================
// A f32 [M x 128] (+ optional extra). K=128 via 4x mfma 16x16x32, bf16 operands, fp32 acc.
// Block 512 thr = 8 waves = 32 rows x 128 cols; grid MN/32 = 256.
// FUSE=1 (QKV mode, NW=3): s0 -> C0 f32 (Qp); s1 -> Kb bf16 flat; s2 -> Vt bf16 transposed+pi.
// FUSE=0: s0 -> C0 f32 (RELU: staged + relu(gemm+b)); s1 -> C1 f32.
template<int NW, int RELU, int NEXTRA, int FUSE>
__global__ __launch_bounds__(512) void k_linm(
        const float* __restrict__ A, const float* __restrict__ extra,
        const HB* __restrict__ Wt0, const float* __restrict__ b0,
        const HB* __restrict__ Wt1, const float* __restrict__ b1,
        const HB* __restrict__ Wt2, const float* __restrict__ b2,
        float* __restrict__ C0, float* __restrict__ C1,
        HB* __restrict__ Kb, HB* __restrict__ Vt) {
    const int tid = threadIdx.x;
    const int w = tid >> 6, lane = tid & 63, l15 = lane & 15, quad = lane >> 4;
    const int row0 = blockIdx.x * 32 + (w >> 2) * 16;
    const int cbase = (w & 3) * 32;

    // A-frags: A[row=l15][k=quad*8+j] packed bf16
    short8 af[4];
    #pragma unroll
    for (int kc = 0; kc < 4; ++kc) {
        const float* ap = A + (size_t)(row0 + l15) * 128 + kc * 32 + quad * 8;
        float4 x0 = *(const float4*)ap;
        float4 x1 = *(const float4*)(ap + 4);
        if (NEXTRA) {
            const float* ep = extra + (size_t)(row0 + l15) * 128 + kc * 32 + quad * 8;
            float4 e0 = *(const float4*)ep, e1 = *(const float4*)(ep + 4);
            x0.x += e0.x; x0.y += e0.y; x0.z += e0.z; x0.w += e0.w;
            x1.x += e1.x; x1.y += e1.y; x1.z += e1.z; x1.w += e1.w;
        }
        uint4v u;
        u[0] = pk2(x0.x, x0.y); u[1] = pk2(x0.z, x0.w);
        u[2] = pk2(x1.x, x1.y); u[3] = pk2(x1.z, x1.w);
        af[kc] = __builtin_bit_cast(short8, u);
    }

    f32x4 zero = {0.f, 0.f, 0.f, 0.f};
    #pragma unroll
    for (int ct = 0; ct < 2; ++ct) {
        const int col = cbase + ct * 16 + l15;
        #pragma unroll
        for (int s = 0; s < NW; ++s) {
            const HB* Wt = (s == 0) ? Wt0 : (s == 1) ? Wt1 : Wt2;
            const float* bs = (s == 0) ? b0 : (s == 1) ? b1 : b2;
            f32x4 acc = zero;
            #pragma unroll
            for (int kc = 0; kc < 4; ++kc) {
                short8 bf = *(const short8*)((const short*)Wt + ((size_t)(kc * 4 + quad) * 128 + col) * 8);
                acc = __builtin_amdgcn_mfma_f32_16x16x32_bf16(af[kc], bf, acc, 0, 0, 0);
            }
            float bb = bs[col];
            if (s == 0 || !FUSE) {
                float* Cs = (s == 0) ? C0 : C1;
                #pragma unroll
                for (int r = 0; r < 4; ++r) {
                    int row = row0 + quad * 4 + r;
                    float v = acc[r] + bb;
                    if (RELU && s == 0) {
                        float st = A[(size_t)row * 128 + col];
                        if (NEXTRA) st += extra[(size_t)row * 128 + col];
                        v = fmaxf(v, 0.f) + st;
                    }
                    Cs[(size_t)row * 128 + col] = v;
                }
            } else if (s == 1) {            // FUSE: K -> bf16 flat [global_row][128]
                #pragma unroll
                for (int r = 0; r < 4; ++r) {
                    int row = row0 + quad * 4 + r;
                    ((unsigned short*)Kb)[(size_t)row * 128 + col] = f2bh(acc[r] + bb);
                }
            } else {                        // FUSE: V -> Vt bf16 [bh][dh][2048], pi-permuted n
                int b_ = row0 >> 11;
                int mloc = (row0 + quad * 4) & 2047;                 // 4-aligned group
                int slotb = (mloc & ~31) + (((mloc & 15) >> 2) << 3) + (((mloc >> 4) & 1) << 2);
                int h_ = col >> 5, dh = col & 31;
                uint2v pv;
                pv[0] = pk2(acc[0] + bb, acc[1] + bb);
                pv[1] = pk2(acc[2] + bb, acc[3] + bb);
                *(short4v*)((short*)Vt + ((size_t)((b_ * 4 + h_) * 32 + dh)) * 2048 + slotb)
                    = __builtin_bit_cast(short4v, pv);
            }
        }
    }
}

// ================= MFMA sigmoid attention (R7 structure + unroll-2) =================
__global__ __launch_bounds__(256) void k_attn3(const float* __restrict__ Qp, const HB* __restrict__ Kbf,
                                               const HB* __restrict__ Vt, float* __restrict__ Opart) {
    const int tid = threadIdx.x;
    const int w = tid >> 6, lane = tid & 63, l15 = lane & 15, quad = lane >> 4;
    const int bh = blockIdx.x >> 6, qg = blockIdx.x & 63;
    const int b = bh >> 2, h = bh & 3;

    __shared__ float ldsacc[4][32][36];

    const float nscale = -0.08838834764831845f;   // -1/sqrt(128)

    short8 aq[2];
    #pragma unroll
    for (int qa = 0; qa < 2; ++qa) {
        const float* qp = Qp + (size_t)(b * Nn + qg * 32 + qa * 16 + l15) * 128 + h * 32 + quad * 8;
        float4 q0 = *(const float4*)qp;
        float4 q1 = *(const float4*)(qp + 4);
        uint4v u;
        u[0] = pk2(q0.x, q0.y); u[1] = pk2(q0.z, q0.w);
        u[2] = pk2(q1.x, q1.y); u[3] = pk2(q1.z, q1.w);
        aq[qa] = __builtin_bit_cast(short8, u);
    }

    f32x4 zero = {0.f, 0.f, 0.f, 0.f};
    f32x4 o[2][2];
    o[0][0] = zero; o[0][1] = zero; o[1][0] = zero; o[1][1] = zero;

    const short* Kb = (const short*)Kbf + (size_t)b * Nn * 128 + h * 32;
    const short* Vb = (const short*)Vt + (size_t)bh * 32 * Nn;

    #pragma unroll 2
    for (int m0 = w * 512; m0 < w * 512 + 512; m0 += 64) {
        short8 kb[4];
        #pragma unroll
        for (int mc = 0; mc < 4; ++mc)
            kb[mc] = *(const short8*)(Kb + (size_t)(m0 + mc * 16 + l15) * 128 + quad * 8);
        short8 vf[2][2];
        #pragma unroll
        for (int t = 0; t < 2; ++t)
            #pragma unroll
            for (int u = 0; u < 2; ++u)
                vf[t][u] = *(const short8*)(Vb + (size_t)(t * 16 + l15) * Nn + m0 + u * 32 + quad * 8);

        #pragma unroll
        for (int qa = 0; qa < 2; ++qa) {
            f32x4 s[4];
            #pragma unroll
            for (int mc = 0; mc < 4; ++mc)
                s[mc] = __builtin_amdgcn_mfma_f32_16x16x32_bf16(kb[mc], aq[qa], zero, 0, 0, 0);
            #pragma unroll
            for (int u = 0; u < 2; ++u) {
                f32x4 lo = s[2 * u], hi = s[2 * u + 1];
                float p0 = __builtin_amdgcn_rcpf(1.f + __expf(lo[0] * nscale));
                float p1 = __builtin_amdgcn_rcpf(1.f + __expf(lo[1] * nscale));
                float p2 = __builtin_amdgcn_rcpf(1.f + __expf(lo[2] * nscale));
                float p3 = __builtin_amdgcn_rcpf(1.f + __expf(lo[3] * nscale));
                float p4 = __builtin_amdgcn_rcpf(1.f + __expf(hi[0] * nscale));
                float p5 = __builtin_amdgcn_rcpf(1.f + __expf(hi[1] * nscale));
                float p6 = __builtin_amdgcn_rcpf(1.f + __expf(hi[2] * nscale));
                float p7 = __builtin_amdgcn_rcpf(1.f + __expf(hi[3] * nscale));
                uint4v pu;
                pu[0] = pk2(p0, p1); pu[1] = pk2(p2, p3);
                pu[2] = pk2(p4, p5); pu[3] = pk2(p6, p7);
                short8 pf = __builtin_bit_cast(short8, pu);
                #pragma unroll
                for (int t = 0; t < 2; ++t)
                    o[qa][t] = __builtin_amdgcn_mfma_f32_16x16x32_bf16(vf[t][u], pf, o[qa][t], 0, 0, 0);
            }
        }
    }

    #pragma unroll
    for (int qa = 0; qa < 2; ++qa)
        #pragma unroll
        for (int t = 0; t < 2; ++t)
            *(f32x4*)&ldsacc[w][qa * 16 + l15][t * 16 + quad * 4] = o[qa][t];
    __syncthreads();
    const int row = tid >> 3, cc = (tid & 7) * 4;
    f32x4 r0 = *(f32x4*)&ldsacc[0][row][cc];
    f32x4 r1 = *(f32x4*)&ldsacc[1][row][cc];
    f32x4 r2 = *(f32x4*)&ldsacc[2][row][cc];
    f32x4 r3 = *(f32x4*)&ldsacc[3][row][cc];
    f32x4 sum = (r0 + r1) + (r2 + r3);
    *(f32x4*)(Opart + (size_t)(b * Nn + qg * 32 + row) * 128 + h * 32 + cc) = sum;
}

// ================= PMA attention, 8-way m-split partials (UNCHANGED, passing) =================
__global__ void k_pma2(const float* __restrict__ S, const float* __restrict__ Wq, const float* __restrict__ bq,
                       const float* __restrict__ Kp, const float* __restrict__ Vp,
                       float* __restrict__ P0part) {
    const int bh = blockIdx.x, b = bh >> 2, h = bh & 3;
    const int ms = blockIdx.y;
    const int tid = threadIdx.x;
    __shared__ float4 qs4[8];
    float* qs = (float*)qs4;
    if (tid < 32) {
        float a = bq[h * 32 + tid];
        for (int k = 0; k < 128; ++k)
            a = fmaf(S[k], Wq[k * Dm + h * 32 + tid], a);
        qs[tid] = a;
    }
    __syncthreads();

    float4 q[8];
    #pragma unroll
    for (int i = 0; i < 8; ++i) q[i] = qs4[i];

    const size_t base = (size_t)b * Nn * Dm + h * 32;
    const float nscale = -0.08838834764831845f;
    const int m = ms * 256 + tid;

    const float4* kp = (const float4*)(Kp + base + (size_t)m * Dm);
    const float4* vp = (const float4*)(Vp + base + (size_t)m * Dm);
    float d0 = 0.f, d1 = 0.f, d2 = 0.f, d3 = 0.f;
    #pragma unroll
    for (int c = 0; c < 8; c += 4) {
        float4 k0 = kp[c+0], k1 = kp[c+1], k2 = kp[c+2], k3 = kp[c+3];
        d0 += q[c+0].x*k0.x + q[c+0].y*k0.y + q[c+0].z*k0.z + q[c+0].w*k0.w;
        d1 += q[c+1].x*k1.x + q[c+1].y*k1.y + q[c+1].z*k1.z + q[c+1].w*k1.w;
        d2 += q[c+2].x*k2.x + q[c+2].y*k2.y + q[c+2].z*k2.z + q[c+2].w*k2.w;
        d3 += q[c+3].x*k3.x + q[c+3].y*k3.y + q[c+3].z*k3.z + q[c+3].w*k3.w;
    }
    float dot = (d0 + d1) + (d2 + d3);
    float a = __builtin_amdgcn_rcpf(1.f + __expf(dot * nscale));
    float4 acc[8];
    #pragma unroll
    for (int c = 0; c < 8; ++c) {
        float4 vv = vp[c];
        acc[c].x = a * vv.x; acc[c].y = a * vv.y; acc[c].z = a * vv.z; acc[c].w = a * vv.w;
    }
    #pragma unroll
    for (int off = 1; off < 64; off <<= 1) {
        #pragma unroll
        for (int c = 0; c < 8; ++c) {
            acc[c].x += __shfl_xor(acc[c].x, off);
            acc[c].y += __shfl_xor(acc[c].y, off);
            acc[c].z += __shfl_xor(acc[c].z, off);
            acc[c].w += __shfl_xor(acc[c].w, off);
        }
    }
    __shared__ float red[4][32];
    const int wave = tid >> 6, lane = tid & 63;
    if (lane == 0) {
        #pragma unroll
        for (int c = 0; c < 8; ++c) {
            red[wave][c*4+0] = acc[c].x; red[wave][c*4+1] = acc[c].y;
            red[wave][c*4+2] = acc[c].z; red[wave][c*4+3] = acc[c].w;
        }
    }
    __syncthreads();
    if (tid < 32) {
        float t = (red[0][tid] + red[1][tid]) + (red[2][tid] + red[3][tid]);
        if (ms == 0) t += qs[tid];
        P0part[ms * 512 + b * 128 + h * 32 + tid] = t;
    }
}

// ================= tiny VALU linear (M=4 only) =================
__global__ __launch_bounds__(256) void k_lin_small(
                      const float* __restrict__ A,
                      const float* __restrict__ extra, int nextra, int estride,
                      const float* __restrict__ W0, const float* __restrict__ b0,
                      int M, float* __restrict__ C0) {
    __shared__ float ldsf[16 * 128];
    const int tid = threadIdx.x;

    #pragma unroll
    for (int it = 0; it < 2; ++it) {
        int f = it * 256 + tid;
        int r = f >> 5, c = f & 31;
        float4 v = make_float4(0.f, 0.f, 0.f, 0.f);
        if (r < M) {
            v = ((const float4*)(A + (size_t)r * 128))[c];
            for (int e = 0; e < nextra; ++e) {
                float4 w = ((const float4*)(extra + (size_t)e * estride + (size_t)r * 128))[c];
                v.x += w.x; v.y += w.y; v.z += w.z; v.w += w.w;
            }
        }
        ((float4*)ldsf)[f] = v;
    }
    __syncthreads();

    const int col = tid & 127;
    const int rg  = tid >> 7;                    // rows rg, rg+2
    float acc[2] = {0.f, 0.f};
    #pragma unroll 8
    for (int k = 0; k < 128; ++k) {
        float w = W0[k * 128 + col];
        acc[0] = fmaf(ldsf[rg * 128 + k], w, acc[0]);
        acc[1] = fmaf(ldsf[(rg + 2) * 128 + k], w, acc[1]);
    }
    float bb = b0[col];
    #pragma unroll
    for (int i = 0; i < 2; ++i) {
        int r = rg + 2 * i;
        if (r < M) {
            float v = fmaxf(acc[i] + bb, 0.f) + ldsf[r * 128 + col];
            C0[(size_t)r * 128 + col] = v;
        }
    }
}

// ================= final projection (UNCHANGED, passing) =================
__global__ void k_final(const float* __restrict__ P, const float* __restrict__ pW,
                        const float* __restrict__ pb, float* __restrict__ out) {
    const int b = blockIdx.x, c = threadIdx.x;
    __shared__ float ps[128];
    if (c < 128) ps[c] = P[b * Dm + c];
    __syncthreads();
    float a = pb[c];
    #pragma unroll 8
    for (int k = 0; k < 128; ++k)
        a = fmaf(ps[k], pW[k * 256 + c], a);
    out[b * 256 + c] = a;
}

extern "C" void kernel_launch(void* const* d_in, const int* in_sizes, int n_in,
                              void* d_out, int out_size, void* d_ws, size_t ws_size,
                              hipStream_t stream) {
    const float* X = (const float*)d_in[0];
    auto W = [&](int i) { return (const float*)d_in[i]; };
    float* ws = (float*)d_ws;

    // slots of SZ floats (4 MB):
    //  s0: Qp0 -> Qp1 -> K2
    //  s1: X1 -> P0part/Pp
    //  s2: Opart0 -> Opart1 -> V2
    //  s3: X2
    //  s4: Kbf(2MB) + Vt(2MB) bf16
    //  s5: WtAll (10 x 32KB bf16)
    float* s0 = ws + 0 * SZ;
    float* s1 = ws + 1 * SZ;
    float* s2 = ws + 2 * SZ;
    float* s3 = ws + 3 * SZ;
    HB*    Kbf = (HB*)(ws + 4 * SZ);
    HB*    Vt  = Kbf + SZ;
    HB*    WtAll = (HB*)(ws + 5 * SZ);
    auto Wt = [&](int idx) { return (const HB*)(WtAll + (size_t)idx * 16384); };
    float* P0part = s1;                 // 8 x 512 floats (X1 dead by then)
    float* Pp     = s1 + 8192;          // 512 floats

    const int GLM = MN / 32;            // 256 blocks for k_linm
    const int attn_blocks = Bn * Hh * (Nn / 32);   // 1024
    dim3 pma_grid(Bn * Hh, 8);
    const float* nul = nullptr;
    const HB* nulh = nullptr;
    HB* nulhm = nullptr;

    // ---- weight pre-swizzle: [W1,W3,W5,W7,W9,W11,W13,W15,W19,W21] -> idx 0..9 ----
    k_wprep<<<10, 256, 0, stream>>>(W(1), W(3), W(5), W(7), W(9), W(11), W(13), W(15),
                                    W(19), W(21), WtAll);

    // ---- SAB layer 0 ----
    k_linm<3,0,0,1><<<GLM, 512, 0, stream>>>(X, nul, Wt(0), W(2), Wt(1), W(4), Wt(2), W(6),
                                             s0, nullptr, Kbf, Vt);          // Qp0, Kbf, Vt
    k_attn3<<<attn_blocks, 256, 0, stream>>>(s0, Kbf, Vt, s2);               // Opart0
    k_linm<1,1,1,0><<<GLM, 512, 0, stream>>>(s0, s2, Wt(3), W(8), nulh, nul, nulh, nul,
                                             s1, nullptr, nulhm, nulhm);     // X1

    // ---- SAB layer 1 ----
    k_linm<3,0,0,1><<<GLM, 512, 0, stream>>>(s1, nul, Wt(4), W(10), Wt(5), W(12), Wt(6), W(14),
                                             s0, nullptr, Kbf, Vt);          // Qp1, Kbf, Vt
    k_attn3<<<attn_blocks, 256, 0, stream>>>(s0, Kbf, Vt, s2);               // Opart1
    k_linm<1,1,1,0><<<GLM, 512, 0, stream>>>(s0, s2, Wt(7), W(16), nulh, nul, nulh, nul,
                                             s3, nullptr, nulhm, nulhm);     // X2

    // ---- PMA ----
    k_linm<2,0,0,0><<<GLM, 512, 0, stream>>>(s3, nul, Wt(8), W(20), Wt(9), W(22), nulh, nul,
                                             s0, s2, nulhm, nulhm);          // K2, V2
    k_pma2<<<pma_grid, 256, 0, stream>>>((const float*)d_in[25], W(17), W(18), s0, s2, P0part);
    k_lin_small<<<1, 256, 0, stream>>>(P0part, P0part + 512, 7, 512, W(23), W(24), Bn, Pp);

    // ---- final projection ----
    k_final<<<Bn, 256, 0, stream>>>(Pp, (const float*)d_in[26], (const float*)d_in[27], (float*)d_out);
}

// Round 9
// 227.473 us; speedup vs baseline: 1.8565x; 1.0405x over previous
//
#include <hip/hip_runtime.h>
#include <hip/hip_bf16.h>

typedef __hip_bfloat16 HB;
typedef __attribute__((ext_vector_type(8))) short short8;
typedef __attribute__((ext_vector_type(4))) short short4v;
typedef __attribute__((ext_vector_type(4))) float f32x4;
typedef __attribute__((ext_vector_type(2))) unsigned int uint2v;
typedef __attribute__((ext_vector_type(4))) unsigned int uint4v;

constexpr int Bn = 4, Nn = 2048, Dm = 128, Hh = 4;
constexpr int MN = Bn * Nn;              // 8192 rows
constexpr size_t SZ = (size_t)MN * Dm;   // 1,048,576 elems per [B,N,128] buffer

static __device__ __forceinline__ short f2bs(float x) {   // RNE
    __hip_bfloat16 h = __float2bfloat16(x);
    return __builtin_bit_cast(short, h);
}
static __device__ __forceinline__ unsigned short f2bh(float x) {  // round-half-up
    return (unsigned short)((__builtin_bit_cast(unsigned int, x) + 0x8000u) >> 16);
}
// round-half-up bf16 pack of two f32 -> one u32
static __device__ __forceinline__ unsigned int pk2(float lo, float hi) {
    unsigned int a = __builtin_bit_cast(unsigned int, lo) + 0x8000u;
    unsigned int b = __builtin_bit_cast(unsigned int, hi) + 0x8000u;
#if __has_builtin(__builtin_amdgcn_perm)
    return __builtin_amdgcn_perm(b, a, 0x07060302u);
#else
    return (a >> 16) | (b & 0xFFFF0000u);
#endif
}

// ================= weight pre-swizzle (4x more parallel than R8) =================
// Wt8[(g*128 + c)*8 + j] = bf16(W[(g*8+j)*128 + c]),  g = k>>3 in [0,16).
__global__ void k_wprep(const float* __restrict__ Wa, const float* __restrict__ Wb,
                        const float* __restrict__ Wc, const float* __restrict__ Wd,
                        const float* __restrict__ We, const float* __restrict__ Wf,
                        const float* __restrict__ Wg, const float* __restrict__ Wh,
                        const float* __restrict__ Wi, const float* __restrict__ Wj,
                        HB* __restrict__ WtAll) {
    const float* src;
    switch (blockIdx.x) {
        case 0: src = Wa; break; case 1: src = Wb; break;
        case 2: src = Wc; break; case 3: src = Wd; break;
        case 4: src = We; break; case 5: src = Wf; break;
        case 6: src = Wg; break; case 7: src = Wh; break;
        case 8: src = Wi; break; default: src = Wj; break;
    }
    HB* dst = WtAll + (size_t)blockIdx.x * 16384;
    #pragma unroll
    for (int it = 0; it < 2; ++it) {
        int idx = blockIdx.y * 512 + it * 256 + threadIdx.x;   // 0..2047
        int g = idx >> 7, c = idx & 127;
        short8 p;
        #pragma unroll
        for (int j = 0; j < 8; ++j) p[j] = f2bs(src[(size_t)(g * 8 + j) * 128 + c]);
        *(short8*)((short*)dst + (size_t)idx * 8) = p;
    }
}

// ================= MFMA linear (QKV0, UNCHANGED from passing R8; only <3,0,0,1> used) ====
template<int NW, int RELU, int NEXTRA, int FUSE>
__global__ __launch_bounds__(512) void k_linm(
        const float* __restrict__ A, const float* __restrict__ extra,
        const HB* __restrict__ Wt0, const float* __restrict__ b0,
        const HB* __restrict__ Wt1, const float* __restrict__ b1,
        const HB* __restrict__ Wt2, const float* __restrict__ b2,
        float* __restrict__ C0, float* __restrict__ C1,
        HB* __restrict__ Kb, HB* __restrict__ Vt) {
    const int tid = threadIdx.x;
    const int w = tid >> 6, lane = tid & 63, l15 = lane & 15, quad = lane >> 4;
    const int row0 = blockIdx.x * 32 + (w >> 2) * 16;
    const int cbase = (w & 3) * 32;

    short8 af[4];
    #pragma unroll
    for (int kc = 0; kc < 4; ++kc) {
        const float* ap = A + (size_t)(row0 + l15) * 128 + kc * 32 + quad * 8;
        float4 x0 = *(const float4*)ap;
        float4 x1 = *(const float4*)(ap + 4);
        if (NEXTRA) {
            const float* ep = extra + (size_t)(row0 + l15) * 128 + kc * 32 + quad * 8;
            float4 e0 = *(const float4*)ep, e1 = *(const float4*)(ep + 4);
            x0.x += e0.x; x0.y += e0.y; x0.z += e0.z; x0.w += e0.w;
            x1.x += e1.x; x1.y += e1.y; x1.z += e1.z; x1.w += e1.w;
        }
        uint4v u;
        u[0] = pk2(x0.x, x0.y); u[1] = pk2(x0.z, x0.w);
        u[2] = pk2(x1.x, x1.y); u[3] = pk2(x1.z, x1.w);
        af[kc] = __builtin_bit_cast(short8, u);
    }

    f32x4 zero = {0.f, 0.f, 0.f, 0.f};
    #pragma unroll
    for (int ct = 0; ct < 2; ++ct) {
        const int col = cbase + ct * 16 + l15;
        #pragma unroll
        for (int s = 0; s < NW; ++s) {
            const HB* Wt = (s == 0) ? Wt0 : (s == 1) ? Wt1 : Wt2;
            const float* bs = (s == 0) ? b0 : (s == 1) ? b1 : b2;
            f32x4 acc = zero;
            #pragma unroll
            for (int kc = 0; kc < 4; ++kc) {
                short8 bf = *(const short8*)((const short*)Wt + ((size_t)(kc * 4 + quad) * 128 + col) * 8);
                acc = __builtin_amdgcn_mfma_f32_16x16x32_bf16(af[kc], bf, acc, 0, 0, 0);
            }
            float bb = bs[col];
            if (s == 0 || !FUSE) {
                float* Cs = (s == 0) ? C0 : C1;
                #pragma unroll
                for (int r = 0; r < 4; ++r) {
                    int row = row0 + quad * 4 + r;
                    float v = acc[r] + bb;
                    if (RELU && s == 0) {
                        float st = A[(size_t)row * 128 + col];
                        if (NEXTRA) st += extra[(size_t)row * 128 + col];
                        v = fmaxf(v, 0.f) + st;
                    }
                    Cs[(size_t)row * 128 + col] = v;
                }
            } else if (s == 1) {
                #pragma unroll
                for (int r = 0; r < 4; ++r) {
                    int row = row0 + quad * 4 + r;
                    ((unsigned short*)Kb)[(size_t)row * 128 + col] = f2bh(acc[r] + bb);
                }
            } else {
                int b_ = row0 >> 11;
                int mloc = (row0 + quad * 4) & 2047;
                int slotb = (mloc & ~31) + (((mloc & 15) >> 2) << 3) + (((mloc >> 4) & 1) << 2);
                int h_ = col >> 5, dh = col & 31;
                uint2v pv;
                pv[0] = pk2(acc[0] + bb, acc[1] + bb);
                pv[1] = pk2(acc[2] + bb, acc[3] + bb);
                *(short4v*)((short*)Vt + ((size_t)((b_ * 4 + h_) * 32 + dh)) * 2048 + slotb)
                    = __builtin_bit_cast(short4v, pv);
            }
        }
    }
}

// ================= fused O-projection + downstream GEMMs =================
// Stage1: X = staged + relu(staged @ WtO + bO), staged = A + extra.  X kept in LDS only.
// Stage2: NQKV GEMMs on X.  FUSE=1: s0->C0 f32 (Q), s1->Kb bf16, s2->Vt bf16 pi-transposed.
//         FUSE=0: s0->C0 f32, s1->C1 f32.
template<int NQKV, int FUSE>
__global__ __launch_bounds__(512) void k_fused(
        const float* __restrict__ A, const float* __restrict__ extra,
        const HB* __restrict__ WtO, const float* __restrict__ bO,
        const HB* __restrict__ Wt0, const float* __restrict__ b0,
        const HB* __restrict__ Wt1, const float* __restrict__ b1,
        const HB* __restrict__ Wt2, const float* __restrict__ b2,
        float* __restrict__ C0, float* __restrict__ C1,
        HB* __restrict__ Kb, HB* __restrict__ Vt) {
    const int tid = threadIdx.x;
    const int w = tid >> 6, lane = tid & 63, l15 = lane & 15, quad = lane >> 4;
    const int lrow0 = (w >> 2) * 16;
    const int row0 = blockIdx.x * 32 + lrow0;
    const int cbase = (w & 3) * 32;

    __shared__ float xs[32 * 132];              // pitch 132 floats (16B-aligned rows)

    // ---- stage A-frags of staged = A + extra ----
    short8 af[4];
    #pragma unroll
    for (int kc = 0; kc < 4; ++kc) {
        const float* ap = A + (size_t)(row0 + l15) * 128 + kc * 32 + quad * 8;
        float4 x0 = *(const float4*)ap;
        float4 x1 = *(const float4*)(ap + 4);
        const float* ep = extra + (size_t)(row0 + l15) * 128 + kc * 32 + quad * 8;
        float4 e0 = *(const float4*)ep, e1 = *(const float4*)(ep + 4);
        x0.x += e0.x; x0.y += e0.y; x0.z += e0.z; x0.w += e0.w;
        x1.x += e1.x; x1.y += e1.y; x1.z += e1.z; x1.w += e1.w;
        uint4v u;
        u[0] = pk2(x0.x, x0.y); u[1] = pk2(x0.z, x0.w);
        u[2] = pk2(x1.x, x1.y); u[3] = pk2(x1.z, x1.w);
        af[kc] = __builtin_bit_cast(short8, u);
    }

    f32x4 zero = {0.f, 0.f, 0.f, 0.f};

    // ---- O-projection GEMM -> X tile into LDS ----
    #pragma unroll
    for (int ct = 0; ct < 2; ++ct) {
        const int col = cbase + ct * 16 + l15;
        f32x4 acc = zero;
        #pragma unroll
        for (int kc = 0; kc < 4; ++kc) {
            short8 bf = *(const short8*)((const short*)WtO + ((size_t)(kc * 4 + quad) * 128 + col) * 8);
            acc = __builtin_amdgcn_mfma_f32_16x16x32_bf16(af[kc], bf, acc, 0, 0, 0);
        }
        float bb = bO[col];
        #pragma unroll
        for (int r = 0; r < 4; ++r) {
            int row = row0 + quad * 4 + r;
            float st = A[(size_t)row * 128 + col] + extra[(size_t)row * 128 + col];
            xs[(lrow0 + quad * 4 + r) * 132 + col] = fmaxf(acc[r] + bb, 0.f) + st;
        }
    }
    __syncthreads();

    // ---- repack X A-frags from LDS ----
    short8 a2[4];
    {
        const float* xrow = xs + (size_t)(lrow0 + l15) * 132;
        #pragma unroll
        for (int kc = 0; kc < 4; ++kc) {
            f32x4 x0 = *(const f32x4*)(xrow + kc * 32 + quad * 8);
            f32x4 x1 = *(const f32x4*)(xrow + kc * 32 + quad * 8 + 4);
            uint4v u;
            u[0] = pk2(x0[0], x0[1]); u[1] = pk2(x0[2], x0[3]);
            u[2] = pk2(x1[0], x1[1]); u[3] = pk2(x1[2], x1[3]);
            a2[kc] = __builtin_bit_cast(short8, u);
        }
    }

    // ---- downstream GEMMs ----
    #pragma unroll
    for (int ct = 0; ct < 2; ++ct) {
        const int col = cbase + ct * 16 + l15;
        #pragma unroll
        for (int s = 0; s < NQKV; ++s) {
            const HB* Wt = (s == 0) ? Wt0 : (s == 1) ? Wt1 : Wt2;
            const float* bs = (s == 0) ? b0 : (s == 1) ? b1 : b2;
            f32x4 acc = zero;
            #pragma unroll
            for (int kc = 0; kc < 4; ++kc) {
                short8 bf = *(const short8*)((const short*)Wt + ((size_t)(kc * 4 + quad) * 128 + col) * 8);
                acc = __builtin_amdgcn_mfma_f32_16x16x32_bf16(a2[kc], bf, acc, 0, 0, 0);
            }
            float bb = bs[col];
            if (s == 0 || !FUSE) {
                float* Cs = (s == 0) ? C0 : C1;
                #pragma unroll
                for (int r = 0; r < 4; ++r) {
                    int row = row0 + quad * 4 + r;
                    Cs[(size_t)row * 128 + col] = acc[r] + bb;
                }
            } else if (s == 1) {
                #pragma unroll
                for (int r = 0; r < 4; ++r) {
                    int row = row0 + quad * 4 + r;
                    ((unsigned short*)Kb)[(size_t)row * 128 + col] = f2bh(acc[r] + bb);
                }
            } else {
                int b_ = row0 >> 11;
                int mloc = (row0 + quad * 4) & 2047;
                int slotb = (mloc & ~31) + (((mloc & 15) >> 2) << 3) + (((mloc >> 4) & 1) << 2);
                int h_ = col >> 5, dh = col & 31;
                uint2v pv;
                pv[0] = pk2(acc[0] + bb, acc[1] + bb);
                pv[1] = pk2(acc[2] + bb, acc[3] + bb);
                *(short4v*)((short*)Vt + ((size_t)((b_ * 4 + h_) * 32 + dh)) * 2048 + slotb)
                    = __builtin_bit_cast(short4v, pv);
            }
        }
    }
}

// ================= MFMA sigmoid attention (UNCHANGED, passing) =================
__global__ __launch_bounds__(256) void k_attn3(const float* __restrict__ Qp, const HB* __restrict__ Kbf,
                                               const HB* __restrict__ Vt, float* __restrict__ Opart) {
    const int tid = threadIdx.x;
    const int w = tid >> 6, lane = tid & 63, l15 = lane & 15, quad = lane >> 4;
    const int bh = blockIdx.x >> 6, qg = blockIdx.x & 63;
    const int b = bh >> 2, h = bh & 3;

    __shared__ float ldsacc[4][32][36];

    const float nscale = -0.08838834764831845f;

    short8 aq[2];
    #pragma unroll
    for (int qa = 0; qa < 2; ++qa) {
        const float* qp = Qp + (size_t)(b * Nn + qg * 32 + qa * 16 + l15) * 128 + h * 32 + quad * 8;
        float4 q0 = *(const float4*)qp;
        float4 q1 = *(const float4*)(qp + 4);
        uint4v u;
        u[0] = pk2(q0.x, q0.y); u[1] = pk2(q0.z, q0.w);
        u[2] = pk2(q1.x, q1.y); u[3] = pk2(q1.z, q1.w);
        aq[qa] = __builtin_bit_cast(short8, u);
    }

    f32x4 zero = {0.f, 0.f, 0.f, 0.f};
    f32x4 o[2][2];
    o[0][0] = zero; o[0][1] = zero; o[1][0] = zero; o[1][1] = zero;

    const short* Kb = (const short*)Kbf + (size_t)b * Nn * 128 + h * 32;
    const short* Vb = (const short*)Vt + (size_t)bh * 32 * Nn;

    #pragma unroll 2
    for (int m0 = w * 512; m0 < w * 512 + 512; m0 += 64) {
        short8 kb[4];
        #pragma unroll
        for (int mc = 0; mc < 4; ++mc)
            kb[mc] = *(const short8*)(Kb + (size_t)(m0 + mc * 16 + l15) * 128 + quad * 8);
        short8 vf[2][2];
        #pragma unroll
        for (int t = 0; t < 2; ++t)
            #pragma unroll
            for (int u = 0; u < 2; ++u)
                vf[t][u] = *(const short8*)(Vb + (size_t)(t * 16 + l15) * Nn + m0 + u * 32 + quad * 8);

        #pragma unroll
        for (int qa = 0; qa < 2; ++qa) {
            f32x4 s[4];
            #pragma unroll
            for (int mc = 0; mc < 4; ++mc)
                s[mc] = __builtin_amdgcn_mfma_f32_16x16x32_bf16(kb[mc], aq[qa], zero, 0, 0, 0);
            #pragma unroll
            for (int u = 0; u < 2; ++u) {
                f32x4 lo = s[2 * u], hi = s[2 * u + 1];
                float p0 = __builtin_amdgcn_rcpf(1.f + __expf(lo[0] * nscale));
                float p1 = __builtin_amdgcn_rcpf(1.f + __expf(lo[1] * nscale));
                float p2 = __builtin_amdgcn_rcpf(1.f + __expf(lo[2] * nscale));
                float p3 = __builtin_amdgcn_rcpf(1.f + __expf(lo[3] * nscale));
                float p4 = __builtin_amdgcn_rcpf(1.f + __expf(hi[0] * nscale));
                float p5 = __builtin_amdgcn_rcpf(1.f + __expf(hi[1] * nscale));
                float p6 = __builtin_amdgcn_rcpf(1.f + __expf(hi[2] * nscale));
                float p7 = __builtin_amdgcn_rcpf(1.f + __expf(hi[3] * nscale));
                uint4v pu;
                pu[0] = pk2(p0, p1); pu[1] = pk2(p2, p3);
                pu[2] = pk2(p4, p5); pu[3] = pk2(p6, p7);
                short8 pf = __builtin_bit_cast(short8, pu);
                #pragma unroll
                for (int t = 0; t < 2; ++t)
                    o[qa][t] = __builtin_amdgcn_mfma_f32_16x16x32_bf16(vf[t][u], pf, o[qa][t], 0, 0, 0);
            }
        }
    }

    #pragma unroll
    for (int qa = 0; qa < 2; ++qa)
        #pragma unroll
        for (int t = 0; t < 2; ++t)
            *(f32x4*)&ldsacc[w][qa * 16 + l15][t * 16 + quad * 4] = o[qa][t];
    __syncthreads();
    const int row = tid >> 3, cc = (tid & 7) * 4;
    f32x4 r0 = *(f32x4*)&ldsacc[0][row][cc];
    f32x4 r1 = *(f32x4*)&ldsacc[1][row][cc];
    f32x4 r2 = *(f32x4*)&ldsacc[2][row][cc];
    f32x4 r3 = *(f32x4*)&ldsacc[3][row][cc];
    f32x4 sum = (r0 + r1) + (r2 + r3);
    *(f32x4*)(Opart + (size_t)(b * Nn + qg * 32 + row) * 128 + h * 32 + cc) = sum;
}

// ================= PMA attention, 8-way m-split partials (UNCHANGED, passing) =================
__global__ void k_pma2(const float* __restrict__ S, const float* __restrict__ Wq, const float* __restrict__ bq,
                       const float* __restrict__ Kp, const float* __restrict__ Vp,
                       float* __restrict__ P0part) {
    const int bh = blockIdx.x, b = bh >> 2, h = bh & 3;
    const int ms = blockIdx.y;
    const int tid = threadIdx.x;
    __shared__ float4 qs4[8];
    float* qs = (float*)qs4;
    if (tid < 32) {
        float a = bq[h * 32 + tid];
        for (int k = 0; k < 128; ++k)
            a = fmaf(S[k], Wq[k * Dm + h * 32 + tid], a);
        qs[tid] = a;
    }
    __syncthreads();

    float4 q[8];
    #pragma unroll
    for (int i = 0; i < 8; ++i) q[i] = qs4[i];

    const size_t base = (size_t)b * Nn * Dm + h * 32;
    const float nscale = -0.08838834764831845f;
    const int m = ms * 256 + tid;

    const float4* kp = (const float4*)(Kp + base + (size_t)m * Dm);
    const float4* vp = (const float4*)(Vp + base + (size_t)m * Dm);
    float d0 = 0.f, d1 = 0.f, d2 = 0.f, d3 = 0.f;
    #pragma unroll
    for (int c = 0; c < 8; c += 4) {
        float4 k0 = kp[c+0], k1 = kp[c+1], k2 = kp[c+2], k3 = kp[c+3];
        d0 += q[c+0].x*k0.x + q[c+0].y*k0.y + q[c+0].z*k0.z + q[c+0].w*k0.w;
        d1 += q[c+1].x*k1.x + q[c+1].y*k1.y + q[c+1].z*k1.z + q[c+1].w*k1.w;
        d2 += q[c+2].x*k2.x + q[c+2].y*k2.y + q[c+2].z*k2.z + q[c+2].w*k2.w;
        d3 += q[c+3].x*k3.x + q[c+3].y*k3.y + q[c+3].z*k3.z + q[c+3].w*k3.w;
    }
    float dot = (d0 + d1) + (d2 + d3);
    float a = __builtin_amdgcn_rcpf(1.f + __expf(dot * nscale));
    float4 acc[8];
    #pragma unroll
    for (int c = 0; c < 8; ++c) {
        float4 vv = vp[c];
        acc[c].x = a * vv.x; acc[c].y = a * vv.y; acc[c].z = a * vv.z; acc[c].w = a * vv.w;
    }
    #pragma unroll
    for (int off = 1; off < 64; off <<= 1) {
        #pragma unroll
        for (int c = 0; c < 8; ++c) {
            acc[c].x += __shfl_xor(acc[c].x, off);
            acc[c].y += __shfl_xor(acc[c].y, off);
            acc[c].z += __shfl_xor(acc[c].z, off);
            acc[c].w += __shfl_xor(acc[c].w, off);
        }
    }
    __shared__ float red[4][32];
    const int wave = tid >> 6, lane = tid & 63;
    if (lane == 0) {
        #pragma unroll
        for (int c = 0; c < 8; ++c) {
            red[wave][c*4+0] = acc[c].x; red[wave][c*4+1] = acc[c].y;
            red[wave][c*4+2] = acc[c].z; red[wave][c*4+3] = acc[c].w;
        }
    }
    __syncthreads();
    if (tid < 32) {
        float t = (red[0][tid] + red[1][tid]) + (red[2][tid] + red[3][tid]);
        if (ms == 0) t += qs[tid];
        P0part[ms * 512 + b * 128 + h * 32 + tid] = t;
    }
}

// ================= fused tail: P0part -> rFF -> final projection -> out =================
__global__ __launch_bounds__(256) void k_tail(const float* __restrict__ P0part,
                                              const float* __restrict__ W23, const float* __restrict__ b23,
                                              const float* __restrict__ pW, const float* __restrict__ pb,
                                              float* __restrict__ out) {
    const int b = blockIdx.x, tid = threadIdx.x;
    __shared__ float staged[128], pp[128];
    if (tid < 128) {
        float s = 0.f;
        #pragma unroll
        for (int ms = 0; ms < 8; ++ms) s += P0part[ms * 512 + b * 128 + tid];
        staged[tid] = s;
    }
    __syncthreads();
    if (tid < 128) {
        float acc = b23[tid];
        #pragma unroll 8
        for (int k = 0; k < 128; ++k)
            acc = fmaf(staged[k], W23[k * 128 + tid], acc);
        pp[tid] = fmaxf(acc, 0.f) + staged[tid];
    }
    __syncthreads();
    float a = pb[tid];
    #pragma unroll 8
    for (int k = 0; k < 128; ++k)
        a = fmaf(pp[k], pW[k * 256 + tid], a);
    out[b * 256 + tid] = a;
}

extern "C" void kernel_launch(void* const* d_in, const int* in_sizes, int n_in,
                              void* d_out, int out_size, void* d_ws, size_t ws_size,
                              hipStream_t stream) {
    const float* X = (const float*)d_in[0];
    auto W = [&](int i) { return (const float*)d_in[i]; };
    float* ws = (float*)d_ws;

    // slots of SZ floats (4 MB):
    //  s0: Qp0 -> K2      s1: Qp1 -> P0part     s2: Opart0/Opart1     s3: V2
    //  s4: Kbf(2MB)+Vt(2MB) bf16     s5: WtAll (10 x 32KB bf16)
    float* s0 = ws + 0 * SZ;
    float* s1 = ws + 1 * SZ;
    float* s2 = ws + 2 * SZ;
    float* s3 = ws + 3 * SZ;
    HB*    Kbf = (HB*)(ws + 4 * SZ);
    HB*    Vt  = Kbf + SZ;
    HB*    WtAll = (HB*)(ws + 5 * SZ);
    auto Wt = [&](int idx) { return (const HB*)(WtAll + (size_t)idx * 16384); };
    float* P0part = s1;

    const int GLM = MN / 32;                       // 256 blocks
    const int attn_blocks = Bn * Hh * (Nn / 32);   // 1024
    dim3 wprep_grid(10, 4);
    dim3 pma_grid(Bn * Hh, 8);
    const float* nul = nullptr;

    // weights pre-swizzle: [W1,W3,W5,W7,W9,W11,W13,W15,W19,W21] -> idx 0..9
    k_wprep<<<wprep_grid, 256, 0, stream>>>(W(1), W(3), W(5), W(7), W(9), W(11), W(13), W(15),
                                            W(19), W(21), WtAll);

    // ---- SAB layer 0: QKV from X ----
    k_linm<3,0,0,1><<<GLM, 512, 0, stream>>>(X, nul, Wt(0), W(2), Wt(1), W(4), Wt(2), W(6),
                                             s0, nullptr, Kbf, Vt);          // Qp0, Kbf, Vt
    k_attn3<<<attn_blocks, 256, 0, stream>>>(s0, Kbf, Vt, s2);               // Opart0

    // ---- oproj0 (+X1 in LDS) + QKV1 ----
    k_fused<3,1><<<GLM, 512, 0, stream>>>(s0, s2, Wt(3), W(8),
                                          Wt(4), W(10), Wt(5), W(12), Wt(6), W(14),
                                          s1, nullptr, Kbf, Vt);             // Qp1, Kbf, Vt
    k_attn3<<<attn_blocks, 256, 0, stream>>>(s1, Kbf, Vt, s2);               // Opart1

    // ---- oproj1 (+X2 in LDS) + PMA K/V projections (f32 out) ----
    k_fused<2,0><<<GLM, 512, 0, stream>>>(s1, s2, Wt(7), W(16),
                                          Wt(8), W(20), Wt(9), W(22), nullptr, nul,
                                          s0, s3, nullptr, nullptr);         // K2, V2

    // ---- PMA attention + tail ----
    k_pma2<<<pma_grid, 256, 0, stream>>>((const float*)d_in[25], W(17), W(18), s0, s3, P0part);
    k_tail<<<Bn, 256, 0, stream>>>(P0part, W(23), W(24), (const float*)d_in[26], (const float*)d_in[27],
                                   (float*)d_out);
}

// Round 10
// 213.528 us; speedup vs baseline: 1.9778x; 1.0653x over previous
//
#include <hip/hip_runtime.h>
#include <hip/hip_bf16.h>

typedef __hip_bfloat16 HB;
typedef __attribute__((ext_vector_type(8))) short short8;
typedef __attribute__((ext_vector_type(4))) short short4v;
typedef __attribute__((ext_vector_type(4))) float f32x4;
typedef __attribute__((ext_vector_type(2))) unsigned int uint2v;
typedef __attribute__((ext_vector_type(4))) unsigned int uint4v;

constexpr int Bn = 4, Nn = 2048, Dm = 128, Hh = 4;
constexpr int MN = Bn * Nn;              // 8192 rows
constexpr size_t SZ = (size_t)MN * Dm;   // 1,048,576 elems per [B,N,128] buffer

static __device__ __forceinline__ short f2bs(float x) {   // RNE
    __hip_bfloat16 h = __float2bfloat16(x);
    return __builtin_bit_cast(short, h);
}
static __device__ __forceinline__ unsigned short f2bh(float x) {  // round-half-up
    return (unsigned short)((__builtin_bit_cast(unsigned int, x) + 0x8000u) >> 16);
}
static __device__ __forceinline__ unsigned int pk2(float lo, float hi) {
    unsigned int a = __builtin_bit_cast(unsigned int, lo) + 0x8000u;
    unsigned int b = __builtin_bit_cast(unsigned int, hi) + 0x8000u;
#if __has_builtin(__builtin_amdgcn_perm)
    return __builtin_amdgcn_perm(b, a, 0x07060302u);
#else
    return (a >> 16) | (b & 0xFFFF0000u);
#endif
}

// ================= weight pre-swizzle (UNCHANGED, passing) =================
__global__ void k_wprep(const float* __restrict__ Wa, const float* __restrict__ Wb,
                        const float* __restrict__ Wc, const float* __restrict__ Wd,
                        const float* __restrict__ We, const float* __restrict__ Wf,
                        const float* __restrict__ Wg, const float* __restrict__ Wh,
                        const float* __restrict__ Wi, const float* __restrict__ Wj,
                        HB* __restrict__ WtAll) {
    const float* src;
    switch (blockIdx.x) {
        case 0: src = Wa; break; case 1: src = Wb; break;
        case 2: src = Wc; break; case 3: src = Wd; break;
        case 4: src = We; break; case 5: src = Wf; break;
        case 6: src = Wg; break; case 7: src = Wh; break;
        case 8: src = Wi; break; default: src = Wj; break;
    }
    HB* dst = WtAll + (size_t)blockIdx.x * 16384;
    #pragma unroll
    for (int it = 0; it < 2; ++it) {
        int idx = blockIdx.y * 512 + it * 256 + threadIdx.x;   // 0..2047
        int g = idx >> 7, c = idx & 127;
        short8 p;
        #pragma unroll
        for (int j = 0; j < 8; ++j) p[j] = f2bs(src[(size_t)(g * 8 + j) * 128 + c]);
        *(short8*)((short*)dst + (size_t)idx * 8) = p;
    }
}

// ================= MFMA linear (FUSE=1: s0 -> Qp f32 AND Qb bf16; s1 -> Kb bf16; s2 -> Vt) =====
template<int NW, int RELU, int NEXTRA, int FUSE>
__global__ __launch_bounds__(512) void k_linm(
        const float* __restrict__ A, const float* __restrict__ extra,
        const HB* __restrict__ Wt0, const float* __restrict__ b0,
        const HB* __restrict__ Wt1, const float* __restrict__ b1,
        const HB* __restrict__ Wt2, const float* __restrict__ b2,
        float* __restrict__ C0, float* __restrict__ C1,
        HB* __restrict__ Qb, HB* __restrict__ Kb, HB* __restrict__ Vt) {
    const int tid = threadIdx.x;
    const int w = tid >> 6, lane = tid & 63, l15 = lane & 15, quad = lane >> 4;
    const int row0 = blockIdx.x * 32 + (w >> 2) * 16;
    const int cbase = (w & 3) * 32;

    short8 af[4];
    #pragma unroll
    for (int kc = 0; kc < 4; ++kc) {
        const float* ap = A + (size_t)(row0 + l15) * 128 + kc * 32 + quad * 8;
        float4 x0 = *(const float4*)ap;
        float4 x1 = *(const float4*)(ap + 4);
        if (NEXTRA) {
            const float* ep = extra + (size_t)(row0 + l15) * 128 + kc * 32 + quad * 8;
            float4 e0 = *(const float4*)ep, e1 = *(const float4*)(ep + 4);
            x0.x += e0.x; x0.y += e0.y; x0.z += e0.z; x0.w += e0.w;
            x1.x += e1.x; x1.y += e1.y; x1.z += e1.z; x1.w += e1.w;
        }
        uint4v u;
        u[0] = pk2(x0.x, x0.y); u[1] = pk2(x0.z, x0.w);
        u[2] = pk2(x1.x, x1.y); u[3] = pk2(x1.z, x1.w);
        af[kc] = __builtin_bit_cast(short8, u);
    }

    f32x4 zero = {0.f, 0.f, 0.f, 0.f};
    #pragma unroll
    for (int ct = 0; ct < 2; ++ct) {
        const int col = cbase + ct * 16 + l15;
        #pragma unroll
        for (int s = 0; s < NW; ++s) {
            const HB* Wt = (s == 0) ? Wt0 : (s == 1) ? Wt1 : Wt2;
            const float* bs = (s == 0) ? b0 : (s == 1) ? b1 : b2;
            f32x4 acc = zero;
            #pragma unroll
            for (int kc = 0; kc < 4; ++kc) {
                short8 bf = *(const short8*)((const short*)Wt + ((size_t)(kc * 4 + quad) * 128 + col) * 8);
                acc = __builtin_amdgcn_mfma_f32_16x16x32_bf16(af[kc], bf, acc, 0, 0, 0);
            }
            float bb = bs[col];
            if (s == 0 || !FUSE) {
                float* Cs = (s == 0) ? C0 : C1;
                #pragma unroll
                for (int r = 0; r < 4; ++r) {
                    int row = row0 + quad * 4 + r;
                    float v = acc[r] + bb;
                    if (RELU && s == 0) {
                        float st = A[(size_t)row * 128 + col];
                        if (NEXTRA) st += extra[(size_t)row * 128 + col];
                        v = fmaxf(v, 0.f) + st;
                    }
                    Cs[(size_t)row * 128 + col] = v;
                    if (FUSE && s == 0)
                        ((unsigned short*)Qb)[(size_t)row * 128 + col] = f2bh(v);
                }
            } else if (s == 1) {
                #pragma unroll
                for (int r = 0; r < 4; ++r) {
                    int row = row0 + quad * 4 + r;
                    ((unsigned short*)Kb)[(size_t)row * 128 + col] = f2bh(acc[r] + bb);
                }
            } else {
                int b_ = row0 >> 11;
                int mloc = (row0 + quad * 4) & 2047;
                int slotb = (mloc & ~31) + (((mloc & 15) >> 2) << 3) + (((mloc >> 4) & 1) << 2);
                int h_ = col >> 5, dh = col & 31;
                uint2v pv;
                pv[0] = pk2(acc[0] + bb, acc[1] + bb);
                pv[1] = pk2(acc[2] + bb, acc[3] + bb);
                *(short4v*)((short*)Vt + ((size_t)((b_ * 4 + h_) * 32 + dh)) * 2048 + slotb)
                    = __builtin_bit_cast(short4v, pv);
            }
        }
    }
}

// ================= fused O-projection + downstream GEMMs =================
template<int NQKV, int FUSE>
__global__ __launch_bounds__(512) void k_fused(
        const float* __restrict__ A, const float* __restrict__ extra,
        const HB* __restrict__ WtO, const float* __restrict__ bO,
        const HB* __restrict__ Wt0, const float* __restrict__ b0,
        const HB* __restrict__ Wt1, const float* __restrict__ b1,
        const HB* __restrict__ Wt2, const float* __restrict__ b2,
        float* __restrict__ C0, float* __restrict__ C1,
        HB* __restrict__ Qb, HB* __restrict__ Kb, HB* __restrict__ Vt) {
    const int tid = threadIdx.x;
    const int w = tid >> 6, lane = tid & 63, l15 = lane & 15, quad = lane >> 4;
    const int lrow0 = (w >> 2) * 16;
    const int row0 = blockIdx.x * 32 + lrow0;
    const int cbase = (w & 3) * 32;

    __shared__ float xs[32 * 132];

    short8 af[4];
    #pragma unroll
    for (int kc = 0; kc < 4; ++kc) {
        const float* ap = A + (size_t)(row0 + l15) * 128 + kc * 32 + quad * 8;
        float4 x0 = *(const float4*)ap;
        float4 x1 = *(const float4*)(ap + 4);
        const float* ep = extra + (size_t)(row0 + l15) * 128 + kc * 32 + quad * 8;
        float4 e0 = *(const float4*)ep, e1 = *(const float4*)(ep + 4);
        x0.x += e0.x; x0.y += e0.y; x0.z += e0.z; x0.w += e0.w;
        x1.x += e1.x; x1.y += e1.y; x1.z += e1.z; x1.w += e1.w;
        uint4v u;
        u[0] = pk2(x0.x, x0.y); u[1] = pk2(x0.z, x0.w);
        u[2] = pk2(x1.x, x1.y); u[3] = pk2(x1.z, x1.w);
        af[kc] = __builtin_bit_cast(short8, u);
    }

    f32x4 zero = {0.f, 0.f, 0.f, 0.f};

    #pragma unroll
    for (int ct = 0; ct < 2; ++ct) {
        const int col = cbase + ct * 16 + l15;
        f32x4 acc = zero;
        #pragma unroll
        for (int kc = 0; kc < 4; ++kc) {
            short8 bf = *(const short8*)((const short*)WtO + ((size_t)(kc * 4 + quad) * 128 + col) * 8);
            acc = __builtin_amdgcn_mfma_f32_16x16x32_bf16(af[kc], bf, acc, 0, 0, 0);
        }
        float bb = bO[col];
        #pragma unroll
        for (int r = 0; r < 4; ++r) {
            int row = row0 + quad * 4 + r;
            float st = A[(size_t)row * 128 + col] + extra[(size_t)row * 128 + col];
            xs[(lrow0 + quad * 4 + r) * 132 + col] = fmaxf(acc[r] + bb, 0.f) + st;
        }
    }
    __syncthreads();

    short8 a2[4];
    {
        const float* xrow = xs + (size_t)(lrow0 + l15) * 132;
        #pragma unroll
        for (int kc = 0; kc < 4; ++kc) {
            f32x4 x0 = *(const f32x4*)(xrow + kc * 32 + quad * 8);
            f32x4 x1 = *(const f32x4*)(xrow + kc * 32 + quad * 8 + 4);
            uint4v u;
            u[0] = pk2(x0[0], x0[1]); u[1] = pk2(x0[2], x0[3]);
            u[2] = pk2(x1[0], x1[1]); u[3] = pk2(x1[2], x1[3]);
            a2[kc] = __builtin_bit_cast(short8, u);
        }
    }

    #pragma unroll
    for (int ct = 0; ct < 2; ++ct) {
        const int col = cbase + ct * 16 + l15;
        #pragma unroll
        for (int s = 0; s < NQKV; ++s) {
            const HB* Wt = (s == 0) ? Wt0 : (s == 1) ? Wt1 : Wt2;
            const float* bs = (s == 0) ? b0 : (s == 1) ? b1 : b2;
            f32x4 acc = zero;
            #pragma unroll
            for (int kc = 0; kc < 4; ++kc) {
                short8 bf = *(const short8*)((const short*)Wt + ((size_t)(kc * 4 + quad) * 128 + col) * 8);
                acc = __builtin_amdgcn_mfma_f32_16x16x32_bf16(a2[kc], bf, acc, 0, 0, 0);
            }
            float bb = bs[col];
            if (s == 0 || !FUSE) {
                float* Cs = (s == 0) ? C0 : C1;
                #pragma unroll
                for (int r = 0; r < 4; ++r) {
                    int row = row0 + quad * 4 + r;
                    float v = acc[r] + bb;
                    Cs[(size_t)row * 128 + col] = v;
                    if (FUSE && s == 0)
                        ((unsigned short*)Qb)[(size_t)row * 128 + col] = f2bh(v);
                }
            } else if (s == 1) {
                #pragma unroll
                for (int r = 0; r < 4; ++r) {
                    int row = row0 + quad * 4 + r;
                    ((unsigned short*)Kb)[(size_t)row * 128 + col] = f2bh(acc[r] + bb);
                }
            } else {
                int b_ = row0 >> 11;
                int mloc = (row0 + quad * 4) & 2047;
                int slotb = (mloc & ~31) + (((mloc & 15) >> 2) << 3) + (((mloc >> 4) & 1) << 2);
                int h_ = col >> 5, dh = col & 31;
                uint2v pv;
                pv[0] = pk2(acc[0] + bb, acc[1] + bb);
                pv[1] = pk2(acc[2] + bb, acc[3] + bb);
                *(short4v*)((short*)Vt + ((size_t)((b_ * 4 + h_) * 32 + dh)) * 2048 + slotb)
                    = __builtin_bit_cast(short4v, pv);
            }
        }
    }
}

// ================= MFMA sigmoid attention v4: 64 q-rows/block, XCD-local bh =================
// grid 512 = qg2*16 + bh  (id%8 == bh%8 -> all blocks of a bh on one XCD; K/V L2-resident).
// 512 thr = 8 waves; wave w: m in [w*256, +256). Qb pre-packed bf16.
__global__ __launch_bounds__(512, 4) void k_attn4(const HB* __restrict__ Qb, const HB* __restrict__ Kbf,
                                                  const HB* __restrict__ Vt, float* __restrict__ Opart) {
    const int tid = threadIdx.x;
    const int w = tid >> 6, lane = tid & 63, l15 = lane & 15, quad = lane >> 4;
    const int bh = blockIdx.x & 15, qg2 = blockIdx.x >> 4;
    const int b = bh >> 2, h = bh & 3;
    const int q0row = qg2 * 64;

    __shared__ float ldsacc[8][64][36];

    const float nscale = -0.08838834764831845f;

    short8 aq[4];
    {
        const short* qp = (const short*)Qb + (size_t)(b * Nn + q0row) * 128 + h * 32 + quad * 8;
        #pragma unroll
        for (int qa = 0; qa < 4; ++qa)
            aq[qa] = *(const short8*)(qp + (size_t)(qa * 16 + l15) * 128);
    }

    f32x4 zero = {0.f, 0.f, 0.f, 0.f};
    f32x4 o[4][2];
    #pragma unroll
    for (int qa = 0; qa < 4; ++qa) { o[qa][0] = zero; o[qa][1] = zero; }

    const short* Kb = (const short*)Kbf + (size_t)b * Nn * 128 + h * 32;
    const short* Vb = (const short*)Vt + (size_t)bh * 32 * Nn;

    for (int m0 = w * 256; m0 < w * 256 + 256; m0 += 64) {
        short8 kb[4];
        #pragma unroll
        for (int mc = 0; mc < 4; ++mc)
            kb[mc] = *(const short8*)(Kb + (size_t)(m0 + mc * 16 + l15) * 128 + quad * 8);
        short8 vf[2][2];
        #pragma unroll
        for (int t = 0; t < 2; ++t)
            #pragma unroll
            for (int u = 0; u < 2; ++u)
                vf[t][u] = *(const short8*)(Vb + (size_t)(t * 16 + l15) * Nn + m0 + u * 32 + quad * 8);

        #pragma unroll
        for (int qa = 0; qa < 4; ++qa) {
            f32x4 s[4];
            #pragma unroll
            for (int mc = 0; mc < 4; ++mc)
                s[mc] = __builtin_amdgcn_mfma_f32_16x16x32_bf16(kb[mc], aq[qa], zero, 0, 0, 0);
            #pragma unroll
            for (int u = 0; u < 2; ++u) {
                f32x4 lo = s[2 * u], hi = s[2 * u + 1];
                float p0 = __builtin_amdgcn_rcpf(1.f + __expf(lo[0] * nscale));
                float p1 = __builtin_amdgcn_rcpf(1.f + __expf(lo[1] * nscale));
                float p2 = __builtin_amdgcn_rcpf(1.f + __expf(lo[2] * nscale));
                float p3 = __builtin_amdgcn_rcpf(1.f + __expf(lo[3] * nscale));
                float p4 = __builtin_amdgcn_rcpf(1.f + __expf(hi[0] * nscale));
                float p5 = __builtin_amdgcn_rcpf(1.f + __expf(hi[1] * nscale));
                float p6 = __builtin_amdgcn_rcpf(1.f + __expf(hi[2] * nscale));
                float p7 = __builtin_amdgcn_rcpf(1.f + __expf(hi[3] * nscale));
                uint4v pu;
                pu[0] = pk2(p0, p1); pu[1] = pk2(p2, p3);
                pu[2] = pk2(p4, p5); pu[3] = pk2(p6, p7);
                short8 pf = __builtin_bit_cast(short8, pu);
                #pragma unroll
                for (int t = 0; t < 2; ++t)
                    o[qa][t] = __builtin_amdgcn_mfma_f32_16x16x32_bf16(vf[t][u], pf, o[qa][t], 0, 0, 0);
            }
        }
    }

    #pragma unroll
    for (int qa = 0; qa < 4; ++qa)
        #pragma unroll
        for (int t = 0; t < 2; ++t)
            *(f32x4*)&ldsacc[w][qa * 16 + l15][t * 16 + quad * 4] = o[qa][t];
    __syncthreads();
    const int row = tid >> 3, cc = (tid & 7) * 4;
    f32x4 sum = zero;
    #pragma unroll
    for (int ww = 0; ww < 8; ++ww) {
        f32x4 r = *(f32x4*)&ldsacc[ww][row][cc];
        sum += r;
    }
    *(f32x4*)(Opart + (size_t)(b * Nn + q0row + row) * 128 + h * 32 + cc) = sum;
}

// ================= PMA attention, 8-way m-split partials (UNCHANGED, passing) =================
__global__ void k_pma2(const float* __restrict__ S, const float* __restrict__ Wq, const float* __restrict__ bq,
                       const float* __restrict__ Kp, const float* __restrict__ Vp,
                       float* __restrict__ P0part) {
    const int bh = blockIdx.x, b = bh >> 2, h = bh & 3;
    const int ms = blockIdx.y;
    const int tid = threadIdx.x;
    __shared__ float4 qs4[8];
    float* qs = (float*)qs4;
    if (tid < 32) {
        float a = bq[h * 32 + tid];
        for (int k = 0; k < 128; ++k)
            a = fmaf(S[k], Wq[k * Dm + h * 32 + tid], a);
        qs[tid] = a;
    }
    __syncthreads();

    float4 q[8];
    #pragma unroll
    for (int i = 0; i < 8; ++i) q[i] = qs4[i];

    const size_t base = (size_t)b * Nn * Dm + h * 32;
    const float nscale = -0.08838834764831845f;
    const int m = ms * 256 + tid;

    const float4* kp = (const float4*)(Kp + base + (size_t)m * Dm);
    const float4* vp = (const float4*)(Vp + base + (size_t)m * Dm);
    float d0 = 0.f, d1 = 0.f, d2 = 0.f, d3 = 0.f;
    #pragma unroll
    for (int c = 0; c < 8; c += 4) {
        float4 k0 = kp[c+0], k1 = kp[c+1], k2 = kp[c+2], k3 = kp[c+3];
        d0 += q[c+0].x*k0.x + q[c+0].y*k0.y + q[c+0].z*k0.z + q[c+0].w*k0.w;
        d1 += q[c+1].x*k1.x + q[c+1].y*k1.y + q[c+1].z*k1.z + q[c+1].w*k1.w;
        d2 += q[c+2].x*k2.x + q[c+2].y*k2.y + q[c+2].z*k2.z + q[c+2].w*k2.w;
        d3 += q[c+3].x*k3.x + q[c+3].y*k3.y + q[c+3].z*k3.z + q[c+3].w*k3.w;
    }
    float dot = (d0 + d1) + (d2 + d3);
    float a = __builtin_amdgcn_rcpf(1.f + __expf(dot * nscale));
    float4 acc[8];
    #pragma unroll
    for (int c = 0; c < 8; ++c) {
        float4 vv = vp[c];
        acc[c].x = a * vv.x; acc[c].y = a * vv.y; acc[c].z = a * vv.z; acc[c].w = a * vv.w;
    }
    #pragma unroll
    for (int off = 1; off < 64; off <<= 1) {
        #pragma unroll
        for (int c = 0; c < 8; ++c) {
            acc[c].x += __shfl_xor(acc[c].x, off);
            acc[c].y += __shfl_xor(acc[c].y, off);
            acc[c].z += __shfl_xor(acc[c].z, off);
            acc[c].w += __shfl_xor(acc[c].w, off);
        }
    }
    __shared__ float red[4][32];
    const int wave = tid >> 6, lane = tid & 63;
    if (lane == 0) {
        #pragma unroll
        for (int c = 0; c < 8; ++c) {
            red[wave][c*4+0] = acc[c].x; red[wave][c*4+1] = acc[c].y;
            red[wave][c*4+2] = acc[c].z; red[wave][c*4+3] = acc[c].w;
        }
    }
    __syncthreads();
    if (tid < 32) {
        float t = (red[0][tid] + red[1][tid]) + (red[2][tid] + red[3][tid]);
        if (ms == 0) t += qs[tid];
        P0part[ms * 512 + b * 128 + h * 32 + tid] = t;
    }
}

// ================= fused tail (UNCHANGED, passing) =================
__global__ __launch_bounds__(256) void k_tail(const float* __restrict__ P0part,
                                              const float* __restrict__ W23, const float* __restrict__ b23,
                                              const float* __restrict__ pW, const float* __restrict__ pb,
                                              float* __restrict__ out) {
    const int b = blockIdx.x, tid = threadIdx.x;
    __shared__ float staged[128], pp[128];
    if (tid < 128) {
        float s = 0.f;
        #pragma unroll
        for (int ms = 0; ms < 8; ++ms) s += P0part[ms * 512 + b * 128 + tid];
        staged[tid] = s;
    }
    __syncthreads();
    if (tid < 128) {
        float acc = b23[tid];
        #pragma unroll 8
        for (int k = 0; k < 128; ++k)
            acc = fmaf(staged[k], W23[k * 128 + tid], acc);
        pp[tid] = fmaxf(acc, 0.f) + staged[tid];
    }
    __syncthreads();
    float a = pb[tid];
    #pragma unroll 8
    for (int k = 0; k < 128; ++k)
        a = fmaf(pp[k], pW[k * 256 + tid], a);
    out[b * 256 + tid] = a;
}

extern "C" void kernel_launch(void* const* d_in, const int* in_sizes, int n_in,
                              void* d_out, int out_size, void* d_ws, size_t ws_size,
                              hipStream_t stream) {
    const float* X = (const float*)d_in[0];
    auto W = [&](int i) { return (const float*)d_in[i]; };
    float* ws = (float*)d_ws;

    // f32 slots (4 MB each): s0: Qp0 -> K2   s1: Qp1 -> P0part   s2: Opart   s3: V2
    // bf16 region at slot 4+: Qb [0,SZ), Kbf [SZ,2SZ), Vt [2SZ,3SZ), WtAll [3SZ,..)
    float* s0 = ws + 0 * SZ;
    float* s1 = ws + 1 * SZ;
    float* s2 = ws + 2 * SZ;
    float* s3 = ws + 3 * SZ;
    HB*    B4  = (HB*)(ws + 4 * SZ);
    HB*    Qb  = B4;
    HB*    Kbf = B4 + SZ;
    HB*    Vt  = B4 + 2 * SZ;
    HB*    WtAll = B4 + 3 * SZ;
    auto Wt = [&](int idx) { return (const HB*)(WtAll + (size_t)idx * 16384); };
    float* P0part = s1;

    const int GLM = MN / 32;                 // 256 blocks
    const int attn_blocks = 512;             // qg2*16 + bh
    dim3 wprep_grid(10, 4);
    dim3 pma_grid(Bn * Hh, 8);
    const float* nul = nullptr;

    k_wprep<<<wprep_grid, 256, 0, stream>>>(W(1), W(3), W(5), W(7), W(9), W(11), W(13), W(15),
                                            W(19), W(21), WtAll);

    // ---- SAB layer 0 ----
    k_linm<3,0,0,1><<<GLM, 512, 0, stream>>>(X, nul, Wt(0), W(2), Wt(1), W(4), Wt(2), W(6),
                                             s0, nullptr, Qb, Kbf, Vt);      // Qp0+Qb, Kbf, Vt
    k_attn4<<<attn_blocks, 512, 0, stream>>>(Qb, Kbf, Vt, s2);               // Opart0

    // ---- oproj0 (+X1 in LDS) + QKV1 ----
    k_fused<3,1><<<GLM, 512, 0, stream>>>(s0, s2, Wt(3), W(8),
                                          Wt(4), W(10), Wt(5), W(12), Wt(6), W(14),
                                          s1, nullptr, Qb, Kbf, Vt);         // Qp1+Qb, Kbf, Vt
    k_attn4<<<attn_blocks, 512, 0, stream>>>(Qb, Kbf, Vt, s2);               // Opart1

    // ---- oproj1 (+X2 in LDS) + PMA K/V projections (f32 out) ----
    k_fused<2,0><<<GLM, 512, 0, stream>>>(s1, s2, Wt(7), W(16),
                                          Wt(8), W(20), Wt(9), W(22), nullptr, nul,
                                          s0, s3, nullptr, nullptr, nullptr);  // K2, V2

    // ---- PMA attention + tail ----
    k_pma2<<<pma_grid, 256, 0, stream>>>((const float*)d_in[25], W(17), W(18), s0, s3, P0part);
    k_tail<<<Bn, 256, 0, stream>>>(P0part, W(23), W(24), (const float*)d_in[26], (const float*)d_in[27],
                                   (float*)d_out);
}

// Round 11
// 208.544 us; speedup vs baseline: 2.0250x; 1.0239x over previous
//
#include <hip/hip_runtime.h>
#include <hip/hip_bf16.h>

typedef __hip_bfloat16 HB;
typedef __attribute__((ext_vector_type(8))) short short8;
typedef __attribute__((ext_vector_type(4))) short short4v;
typedef __attribute__((ext_vector_type(4))) float f32x4;
typedef __attribute__((ext_vector_type(2))) unsigned int uint2v;
typedef __attribute__((ext_vector_type(4))) unsigned int uint4v;

constexpr int Bn = 4, Nn = 2048, Dm = 128, Hh = 4;
constexpr int MN = Bn * Nn;              // 8192 rows
constexpr size_t SZ = (size_t)MN * Dm;   // 1,048,576 elems per [B,N,128] buffer

static __device__ __forceinline__ short f2bs(float x) {   // RNE
    __hip_bfloat16 h = __float2bfloat16(x);
    return __builtin_bit_cast(short, h);
}
static __device__ __forceinline__ unsigned short f2bh(float x) {  // round-half-up
    return (unsigned short)((__builtin_bit_cast(unsigned int, x) + 0x8000u) >> 16);
}
static __device__ __forceinline__ unsigned int pk2(float lo, float hi) {
    unsigned int a = __builtin_bit_cast(unsigned int, lo) + 0x8000u;
    unsigned int b = __builtin_bit_cast(unsigned int, hi) + 0x8000u;
#if __has_builtin(__builtin_amdgcn_perm)
    return __builtin_amdgcn_perm(b, a, 0x07060302u);
#else
    return (a >> 16) | (b & 0xFFFF0000u);
#endif
}
// fast 2^x (v_exp_f32)
static __device__ __forceinline__ float ex2(float x) {
#if __has_builtin(__builtin_amdgcn_exp2f)
    return __builtin_amdgcn_exp2f(x);
#else
    return exp2f(x);
#endif
}
// sigmoid(s/sqrt(128)) with the whole chain folded: rcp(1 + 2^(s*c)), c = -log2e/sqrt(128)
#define NSC2 (-0.12751884772864078f)

// K bf16 head-packed layout: Kh[bh][n][32dh]
static __device__ __forceinline__ size_t kh_idx(int row, int col) {
    return ((size_t)((row >> 11) * 4 + (col >> 5)) * 2048 + (row & 2047)) * 32 + (col & 31);
}

// ================= weight pre-swizzle (UNCHANGED, passing) =================
__global__ void k_wprep(const float* __restrict__ Wa, const float* __restrict__ Wb,
                        const float* __restrict__ Wc, const float* __restrict__ Wd,
                        const float* __restrict__ We, const float* __restrict__ Wf,
                        const float* __restrict__ Wg, const float* __restrict__ Wh,
                        const float* __restrict__ Wi, const float* __restrict__ Wj,
                        HB* __restrict__ WtAll) {
    const float* src;
    switch (blockIdx.x) {
        case 0: src = Wa; break; case 1: src = Wb; break;
        case 2: src = Wc; break; case 3: src = Wd; break;
        case 4: src = We; break; case 5: src = Wf; break;
        case 6: src = Wg; break; case 7: src = Wh; break;
        case 8: src = Wi; break; default: src = Wj; break;
    }
    HB* dst = WtAll + (size_t)blockIdx.x * 16384;
    #pragma unroll
    for (int it = 0; it < 2; ++it) {
        int idx = blockIdx.y * 512 + it * 256 + threadIdx.x;   // 0..2047
        int g = idx >> 7, c = idx & 127;
        short8 p;
        #pragma unroll
        for (int j = 0; j < 8; ++j) p[j] = f2bs(src[(size_t)(g * 8 + j) * 128 + c]);
        *(short8*)((short*)dst + (size_t)idx * 8) = p;
    }
}

// ================= MFMA linear (FUSE=1: s0 -> Qp f32 + Qb bf16; s1 -> Kh bf16; s2 -> Vt) =====
template<int NW, int RELU, int NEXTRA, int FUSE>
__global__ __launch_bounds__(512) void k_linm(
        const float* __restrict__ A, const float* __restrict__ extra,
        const HB* __restrict__ Wt0, const float* __restrict__ b0,
        const HB* __restrict__ Wt1, const float* __restrict__ b1,
        const HB* __restrict__ Wt2, const float* __restrict__ b2,
        float* __restrict__ C0, float* __restrict__ C1,
        HB* __restrict__ Qb, HB* __restrict__ Kb, HB* __restrict__ Vt) {
    const int tid = threadIdx.x;
    const int w = tid >> 6, lane = tid & 63, l15 = lane & 15, quad = lane >> 4;
    const int row0 = blockIdx.x * 32 + (w >> 2) * 16;
    const int cbase = (w & 3) * 32;

    short8 af[4];
    #pragma unroll
    for (int kc = 0; kc < 4; ++kc) {
        const float* ap = A + (size_t)(row0 + l15) * 128 + kc * 32 + quad * 8;
        float4 x0 = *(const float4*)ap;
        float4 x1 = *(const float4*)(ap + 4);
        if (NEXTRA) {
            const float* ep = extra + (size_t)(row0 + l15) * 128 + kc * 32 + quad * 8;
            float4 e0 = *(const float4*)ep, e1 = *(const float4*)(ep + 4);
            x0.x += e0.x; x0.y += e0.y; x0.z += e0.z; x0.w += e0.w;
            x1.x += e1.x; x1.y += e1.y; x1.z += e1.z; x1.w += e1.w;
        }
        uint4v u;
        u[0] = pk2(x0.x, x0.y); u[1] = pk2(x0.z, x0.w);
        u[2] = pk2(x1.x, x1.y); u[3] = pk2(x1.z, x1.w);
        af[kc] = __builtin_bit_cast(short8, u);
    }

    f32x4 zero = {0.f, 0.f, 0.f, 0.f};
    #pragma unroll
    for (int ct = 0; ct < 2; ++ct) {
        const int col = cbase + ct * 16 + l15;
        #pragma unroll
        for (int s = 0; s < NW; ++s) {
            const HB* Wt = (s == 0) ? Wt0 : (s == 1) ? Wt1 : Wt2;
            const float* bs = (s == 0) ? b0 : (s == 1) ? b1 : b2;
            f32x4 acc = zero;
            #pragma unroll
            for (int kc = 0; kc < 4; ++kc) {
                short8 bf = *(const short8*)((const short*)Wt + ((size_t)(kc * 4 + quad) * 128 + col) * 8);
                acc = __builtin_amdgcn_mfma_f32_16x16x32_bf16(af[kc], bf, acc, 0, 0, 0);
            }
            float bb = bs[col];
            if (s == 0 || !FUSE) {
                float* Cs = (s == 0) ? C0 : C1;
                #pragma unroll
                for (int r = 0; r < 4; ++r) {
                    int row = row0 + quad * 4 + r;
                    float v = acc[r] + bb;
                    if (RELU && s == 0) {
                        float st = A[(size_t)row * 128 + col];
                        if (NEXTRA) st += extra[(size_t)row * 128 + col];
                        v = fmaxf(v, 0.f) + st;
                    }
                    Cs[(size_t)row * 128 + col] = v;
                    if (FUSE && s == 0)
                        ((unsigned short*)Qb)[(size_t)row * 128 + col] = f2bh(v);
                }
            } else if (s == 1) {            // K -> head-packed bf16 Kh[bh][n][32]
                #pragma unroll
                for (int r = 0; r < 4; ++r) {
                    int row = row0 + quad * 4 + r;
                    ((unsigned short*)Kb)[kh_idx(row, col)] = f2bh(acc[r] + bb);
                }
            } else {
                int b_ = row0 >> 11;
                int mloc = (row0 + quad * 4) & 2047;
                int slotb = (mloc & ~31) + (((mloc & 15) >> 2) << 3) + (((mloc >> 4) & 1) << 2);
                int h_ = col >> 5, dh = col & 31;
                uint2v pv;
                pv[0] = pk2(acc[0] + bb, acc[1] + bb);
                pv[1] = pk2(acc[2] + bb, acc[3] + bb);
                *(short4v*)((short*)Vt + ((size_t)((b_ * 4 + h_) * 32 + dh)) * 2048 + slotb)
                    = __builtin_bit_cast(short4v, pv);
            }
        }
    }
}

// ================= fused O-projection + downstream GEMMs =================
template<int NQKV, int FUSE>
__global__ __launch_bounds__(512) void k_fused(
        const float* __restrict__ A, const float* __restrict__ extra,
        const HB* __restrict__ WtO, const float* __restrict__ bO,
        const HB* __restrict__ Wt0, const float* __restrict__ b0,
        const HB* __restrict__ Wt1, const float* __restrict__ b1,
        const HB* __restrict__ Wt2, const float* __restrict__ b2,
        float* __restrict__ C0, float* __restrict__ C1,
        HB* __restrict__ Qb, HB* __restrict__ Kb, HB* __restrict__ Vt) {
    const int tid = threadIdx.x;
    const int w = tid >> 6, lane = tid & 63, l15 = lane & 15, quad = lane >> 4;
    const int lrow0 = (w >> 2) * 16;
    const int row0 = blockIdx.x * 32 + lrow0;
    const int cbase = (w & 3) * 32;

    __shared__ float xs[32 * 132];

    short8 af[4];
    #pragma unroll
    for (int kc = 0; kc < 4; ++kc) {
        const float* ap = A + (size_t)(row0 + l15) * 128 + kc * 32 + quad * 8;
        float4 x0 = *(const float4*)ap;
        float4 x1 = *(const float4*)(ap + 4);
        const float* ep = extra + (size_t)(row0 + l15) * 128 + kc * 32 + quad * 8;
        float4 e0 = *(const float4*)ep, e1 = *(const float4*)(ep + 4);
        x0.x += e0.x; x0.y += e0.y; x0.z += e0.z; x0.w += e0.w;
        x1.x += e1.x; x1.y += e1.y; x1.z += e1.z; x1.w += e1.w;
        uint4v u;
        u[0] = pk2(x0.x, x0.y); u[1] = pk2(x0.z, x0.w);
        u[2] = pk2(x1.x, x1.y); u[3] = pk2(x1.z, x1.w);
        af[kc] = __builtin_bit_cast(short8, u);
    }

    f32x4 zero = {0.f, 0.f, 0.f, 0.f};

    #pragma unroll
    for (int ct = 0; ct < 2; ++ct) {
        const int col = cbase + ct * 16 + l15;
        f32x4 acc = zero;
        #pragma unroll
        for (int kc = 0; kc < 4; ++kc) {
            short8 bf = *(const short8*)((const short*)WtO + ((size_t)(kc * 4 + quad) * 128 + col) * 8);
            acc = __builtin_amdgcn_mfma_f32_16x16x32_bf16(af[kc], bf, acc, 0, 0, 0);
        }
        float bb = bO[col];
        #pragma unroll
        for (int r = 0; r < 4; ++r) {
            int row = row0 + quad * 4 + r;
            float st = A[(size_t)row * 128 + col] + extra[(size_t)row * 128 + col];
            xs[(lrow0 + quad * 4 + r) * 132 + col] = fmaxf(acc[r] + bb, 0.f) + st;
        }
    }
    __syncthreads();

    short8 a2[4];
    {
        const float* xrow = xs + (size_t)(lrow0 + l15) * 132;
        #pragma unroll
        for (int kc = 0; kc < 4; ++kc) {
            f32x4 x0 = *(const f32x4*)(xrow + kc * 32 + quad * 8);
            f32x4 x1 = *(const f32x4*)(xrow + kc * 32 + quad * 8 + 4);
            uint4v u;
            u[0] = pk2(x0[0], x0[1]); u[1] = pk2(x0[2], x0[3]);
            u[2] = pk2(x1[0], x1[1]); u[3] = pk2(x1[2], x1[3]);
            a2[kc] = __builtin_bit_cast(short8, u);
        }
    }

    #pragma unroll
    for (int ct = 0; ct < 2; ++ct) {
        const int col = cbase + ct * 16 + l15;
        #pragma unroll
        for (int s = 0; s < NQKV; ++s) {
            const HB* Wt = (s == 0) ? Wt0 : (s == 1) ? Wt1 : Wt2;
            const float* bs = (s == 0) ? b0 : (s == 1) ? b1 : b2;
            f32x4 acc = zero;
            #pragma unroll
            for (int kc = 0; kc < 4; ++kc) {
                short8 bf = *(const short8*)((const short*)Wt + ((size_t)(kc * 4 + quad) * 128 + col) * 8);
                acc = __builtin_amdgcn_mfma_f32_16x16x32_bf16(a2[kc], bf, acc, 0, 0, 0);
            }
            float bb = bs[col];
            if (s == 0 || !FUSE) {
                float* Cs = (s == 0) ? C0 : C1;
                #pragma unroll
                for (int r = 0; r < 4; ++r) {
                    int row = row0 + quad * 4 + r;
                    float v = acc[r] + bb;
                    Cs[(size_t)row * 128 + col] = v;
                    if (FUSE && s == 0)
                        ((unsigned short*)Qb)[(size_t)row * 128 + col] = f2bh(v);
                }
            } else if (s == 1) {            // K -> head-packed bf16 Kh[bh][n][32]
                #pragma unroll
                for (int r = 0; r < 4; ++r) {
                    int row = row0 + quad * 4 + r;
                    ((unsigned short*)Kb)[kh_idx(row, col)] = f2bh(acc[r] + bb);
                }
            } else {
                int b_ = row0 >> 11;
                int mloc = (row0 + quad * 4) & 2047;
                int slotb = (mloc & ~31) + (((mloc & 15) >> 2) << 3) + (((mloc >> 4) & 1) << 2);
                int h_ = col >> 5, dh = col & 31;
                uint2v pv;
                pv[0] = pk2(acc[0] + bb, acc[1] + bb);
                pv[1] = pk2(acc[2] + bb, acc[3] + bb);
                *(short4v*)((short*)Vt + ((size_t)((b_ * 4 + h_) * 32 + dh)) * 2048 + slotb)
                    = __builtin_bit_cast(short4v, pv);
            }
        }
    }
}

// ================= MFMA sigmoid attention v5: Kh layout + exp2 sigmoid =================
// grid 512 = qg2*16 + bh; 512 thr = 8 waves; wave w: m in [w*256, +256).
__global__ __launch_bounds__(512, 4) void k_attn4(const HB* __restrict__ Qb, const HB* __restrict__ Kbf,
                                                  const HB* __restrict__ Vt, float* __restrict__ Opart) {
    const int tid = threadIdx.x;
    const int w = tid >> 6, lane = tid & 63, l15 = lane & 15, quad = lane >> 4;
    const int bh = blockIdx.x & 15, qg2 = blockIdx.x >> 4;
    const int b = bh >> 2, h = bh & 3;
    const int q0row = qg2 * 64;

    __shared__ float ldsacc[8][64][36];

    short8 aq[4];
    {
        const short* qp = (const short*)Qb + (size_t)(b * Nn + q0row) * 128 + h * 32 + quad * 8;
        #pragma unroll
        for (int qa = 0; qa < 4; ++qa)
            aq[qa] = *(const short8*)(qp + (size_t)(qa * 16 + l15) * 128);
    }

    f32x4 zero = {0.f, 0.f, 0.f, 0.f};
    f32x4 o[4][2];
    #pragma unroll
    for (int qa = 0; qa < 4; ++qa) { o[qa][0] = zero; o[qa][1] = zero; }

    const short* Kb = (const short*)Kbf + (size_t)bh * Nn * 32;   // head-packed
    const short* Vb = (const short*)Vt + (size_t)bh * 32 * Nn;

    for (int m0 = w * 256; m0 < w * 256 + 256; m0 += 64) {
        short8 kb[4];
        #pragma unroll
        for (int mc = 0; mc < 4; ++mc)
            kb[mc] = *(const short8*)(Kb + (size_t)(m0 + mc * 16 + l15) * 32 + quad * 8);
        short8 vf[2][2];
        #pragma unroll
        for (int t = 0; t < 2; ++t)
            #pragma unroll
            for (int u = 0; u < 2; ++u)
                vf[t][u] = *(const short8*)(Vb + (size_t)(t * 16 + l15) * Nn + m0 + u * 32 + quad * 8);

        #pragma unroll
        for (int qa = 0; qa < 4; ++qa) {
            f32x4 s[4];
            #pragma unroll
            for (int mc = 0; mc < 4; ++mc)
                s[mc] = __builtin_amdgcn_mfma_f32_16x16x32_bf16(kb[mc], aq[qa], zero, 0, 0, 0);
            #pragma unroll
            for (int u = 0; u < 2; ++u) {
                f32x4 lo = s[2 * u], hi = s[2 * u + 1];
                float p0 = __builtin_amdgcn_rcpf(1.f + ex2(lo[0] * NSC2));
                float p1 = __builtin_amdgcn_rcpf(1.f + ex2(lo[1] * NSC2));
                float p2 = __builtin_amdgcn_rcpf(1.f + ex2(lo[2] * NSC2));
                float p3 = __builtin_amdgcn_rcpf(1.f + ex2(lo[3] * NSC2));
                float p4 = __builtin_amdgcn_rcpf(1.f + ex2(hi[0] * NSC2));
                float p5 = __builtin_amdgcn_rcpf(1.f + ex2(hi[1] * NSC2));
                float p6 = __builtin_amdgcn_rcpf(1.f + ex2(hi[2] * NSC2));
                float p7 = __builtin_amdgcn_rcpf(1.f + ex2(hi[3] * NSC2));
                uint4v pu;
                pu[0] = pk2(p0, p1); pu[1] = pk2(p2, p3);
                pu[2] = pk2(p4, p5); pu[3] = pk2(p6, p7);
                short8 pf = __builtin_bit_cast(short8, pu);
                #pragma unroll
                for (int t = 0; t < 2; ++t)
                    o[qa][t] = __builtin_amdgcn_mfma_f32_16x16x32_bf16(vf[t][u], pf, o[qa][t], 0, 0, 0);
            }
        }
    }

    #pragma unroll
    for (int qa = 0; qa < 4; ++qa)
        #pragma unroll
        for (int t = 0; t < 2; ++t)
            *(f32x4*)&ldsacc[w][qa * 16 + l15][t * 16 + quad * 4] = o[qa][t];
    __syncthreads();
    const int row = tid >> 3, cc = (tid & 7) * 4;
    f32x4 sum = zero;
    #pragma unroll
    for (int ww = 0; ww < 8; ++ww) {
        f32x4 r = *(f32x4*)&ldsacc[ww][row][cc];
        sum += r;
    }
    *(f32x4*)(Opart + (size_t)(b * Nn + q0row + row) * 128 + h * 32 + cc) = sum;
}

// ================= PMA attention, 8-way m-split partials =================
__global__ void k_pma2(const float* __restrict__ S, const float* __restrict__ Wq, const float* __restrict__ bq,
                       const float* __restrict__ Kp, const float* __restrict__ Vp,
                       float* __restrict__ P0part) {
    const int bh = blockIdx.x, b = bh >> 2, h = bh & 3;
    const int ms = blockIdx.y;
    const int tid = threadIdx.x;
    __shared__ float4 qs4[8];
    float* qs = (float*)qs4;
    if (tid < 32) {
        float a = bq[h * 32 + tid];
        for (int k = 0; k < 128; ++k)
            a = fmaf(S[k], Wq[k * Dm + h * 32 + tid], a);
        qs[tid] = a;
    }
    __syncthreads();

    float4 q[8];
    #pragma unroll
    for (int i = 0; i < 8; ++i) q[i] = qs4[i];

    const size_t base = (size_t)b * Nn * Dm + h * 32;
    const int m = ms * 256 + tid;

    const float4* kp = (const float4*)(Kp + base + (size_t)m * Dm);
    const float4* vp = (const float4*)(Vp + base + (size_t)m * Dm);
    float d0 = 0.f, d1 = 0.f, d2 = 0.f, d3 = 0.f;
    #pragma unroll
    for (int c = 0; c < 8; c += 4) {
        float4 k0 = kp[c+0], k1 = kp[c+1], k2 = kp[c+2], k3 = kp[c+3];
        d0 += q[c+0].x*k0.x + q[c+0].y*k0.y + q[c+0].z*k0.z + q[c+0].w*k0.w;
        d1 += q[c+1].x*k1.x + q[c+1].y*k1.y + q[c+1].z*k1.z + q[c+1].w*k1.w;
        d2 += q[c+2].x*k2.x + q[c+2].y*k2.y + q[c+2].z*k2.z + q[c+2].w*k2.w;
        d3 += q[c+3].x*k3.x + q[c+3].y*k3.y + q[c+3].z*k3.z + q[c+3].w*k3.w;
    }
    float dot = (d0 + d1) + (d2 + d3);
    float a = __builtin_amdgcn_rcpf(1.f + ex2(dot * NSC2));
    float4 acc[8];
    #pragma unroll
    for (int c = 0; c < 8; ++c) {
        float4 vv = vp[c];
        acc[c].x = a * vv.x; acc[c].y = a * vv.y; acc[c].z = a * vv.z; acc[c].w = a * vv.w;
    }
    #pragma unroll
    for (int off = 1; off < 64; off <<= 1) {
        #pragma unroll
        for (int c = 0; c < 8; ++c) {
            acc[c].x += __shfl_xor(acc[c].x, off);
            acc[c].y += __shfl_xor(acc[c].y, off);
            acc[c].z += __shfl_xor(acc[c].z, off);
            acc[c].w += __shfl_xor(acc[c].w, off);
        }
    }
    __shared__ float red[4][32];
    const int wave = tid >> 6, lane = tid & 63;
    if (lane == 0) {
        #pragma unroll
        for (int c = 0; c < 8; ++c) {
            red[wave][c*4+0] = acc[c].x; red[wave][c*4+1] = acc[c].y;
            red[wave][c*4+2] = acc[c].z; red[wave][c*4+3] = acc[c].w;
        }
    }
    __syncthreads();
    if (tid < 32) {
        float t = (red[0][tid] + red[1][tid]) + (red[2][tid] + red[3][tid]);
        if (ms == 0) t += qs[tid];
        P0part[ms * 512 + b * 128 + h * 32 + tid] = t;
    }
}

// ================= fused tail (UNCHANGED, passing) =================
__global__ __launch_bounds__(256) void k_tail(const float* __restrict__ P0part,
                                              const float* __restrict__ W23, const float* __restrict__ b23,
                                              const float* __restrict__ pW, const float* __restrict__ pb,
                                              float* __restrict__ out) {
    const int b = blockIdx.x, tid = threadIdx.x;
    __shared__ float staged[128], pp[128];
    if (tid < 128) {
        float s = 0.f;
        #pragma unroll
        for (int ms = 0; ms < 8; ++ms) s += P0part[ms * 512 + b * 128 + tid];
        staged[tid] = s;
    }
    __syncthreads();
    if (tid < 128) {
        float acc = b23[tid];
        #pragma unroll 8
        for (int k = 0; k < 128; ++k)
            acc = fmaf(staged[k], W23[k * 128 + tid], acc);
        pp[tid] = fmaxf(acc, 0.f) + staged[tid];
    }
    __syncthreads();
    float a = pb[tid];
    #pragma unroll 8
    for (int k = 0; k < 128; ++k)
        a = fmaf(pp[k], pW[k * 256 + tid], a);
    out[b * 256 + tid] = a;
}

extern "C" void kernel_launch(void* const* d_in, const int* in_sizes, int n_in,
                              void* d_out, int out_size, void* d_ws, size_t ws_size,
                              hipStream_t stream) {
    const float* X = (const float*)d_in[0];
    auto W = [&](int i) { return (const float*)d_in[i]; };
    float* ws = (float*)d_ws;

    float* s0 = ws + 0 * SZ;
    float* s1 = ws + 1 * SZ;
    float* s2 = ws + 2 * SZ;
    float* s3 = ws + 3 * SZ;
    HB*    B4  = (HB*)(ws + 4 * SZ);
    HB*    Qb  = B4;
    HB*    Kbf = B4 + SZ;        // head-packed Kh[16][2048][32]
    HB*    Vt  = B4 + 2 * SZ;
    HB*    WtAll = B4 + 3 * SZ;
    auto Wt = [&](int idx) { return (const HB*)(WtAll + (size_t)idx * 16384); };
    float* P0part = s1;

    const int GLM = MN / 32;                 // 256 blocks
    const int attn_blocks = 512;             // qg2*16 + bh
    dim3 wprep_grid(10, 4);
    dim3 pma_grid(Bn * Hh, 8);
    const float* nul = nullptr;

    k_wprep<<<wprep_grid, 256, 0, stream>>>(W(1), W(3), W(5), W(7), W(9), W(11), W(13), W(15),
                                            W(19), W(21), WtAll);

    // ---- SAB layer 0 ----
    k_linm<3,0,0,1><<<GLM, 512, 0, stream>>>(X, nul, Wt(0), W(2), Wt(1), W(4), Wt(2), W(6),
                                             s0, nullptr, Qb, Kbf, Vt);      // Qp0+Qb, Kh, Vt
    k_attn4<<<attn_blocks, 512, 0, stream>>>(Qb, Kbf, Vt, s2);               // Opart0

    // ---- oproj0 (+X1 in LDS) + QKV1 ----
    k_fused<3,1><<<GLM, 512, 0, stream>>>(s0, s2, Wt(3), W(8),
                                          Wt(4), W(10), Wt(5), W(12), Wt(6), W(14),
                                          s1, nullptr, Qb, Kbf, Vt);         // Qp1+Qb, Kh, Vt
    k_attn4<<<attn_blocks, 512, 0, stream>>>(Qb, Kbf, Vt, s2);               // Opart1

    // ---- oproj1 (+X2 in LDS) + PMA K/V projections (f32 out) ----
    k_fused<2,0><<<GLM, 512, 0, stream>>>(s1, s2, Wt(7), W(16),
                                          Wt(8), W(20), Wt(9), W(22), nullptr, nul,
                                          s0, s3, nullptr, nullptr, nullptr);  // K2, V2

    // ---- PMA attention + tail ----
    k_pma2<<<pma_grid, 256, 0, stream>>>((const float*)d_in[25], W(17), W(18), s0, s3, P0part);
    k_tail<<<Bn, 256, 0, stream>>>(P0part, W(23), W(24), (const float*)d_in[26], (const float*)d_in[27],
                                   (float*)d_out);
}